// Round 6
// baseline (287.625 us; speedup 1.0000x reference)
//
#include <hip/hip_runtime.h>
#include <math.h>

#define EMBED 1024
#define HEADS 16
#define HD 64
#define BATCH 4
#define TSEQ 4096
#define BH (BATCH * HEADS)
#define MROWS (BATCH * TSEQ)   // 16384

typedef _Float16 f16;
typedef __attribute__((ext_vector_type(4))) _Float16 f16x4;
typedef __attribute__((ext_vector_type(8))) _Float16 f16x8;
typedef __attribute__((ext_vector_type(4))) float f32x4;

#define GLOBAL_AS __attribute__((address_space(1)))
#define LDS_AS __attribute__((address_space(3)))

__device__ __forceinline__ float elu1(float v) {
    return v > 0.f ? v + 1.f : __expf(v);
}

// XOR-swizzled element offset in a [rows][cols] f16 tile; 16B granules.
__device__ __forceinline__ int swzc(int row, int col, int cols) {
    int g = (col >> 3) ^ (row & 7);
    return row * cols + (g << 3) + (col & 7);
}

__device__ __forceinline__ f16x8 fragld(const f16* t, int row, int k, int cols) {
    return *(const f16x8*)&t[swzc(row, k, cols)];
}

__device__ __forceinline__ f32x4 mfma16(f16x8 a, f16x8 b, f32x4 c) {
    return __builtin_amdgcn_mfma_f32_16x16x32_f16(a, b, c, 0, 0, 0);
}

__device__ __forceinline__ void gld_lds16(const f16* g, f16* l) {
    __builtin_amdgcn_global_load_lds((const GLOBAL_AS void*)g, (LDS_AS void*)l, 16, 0, 0);
}

// stage rows [r0, r0+64) of a 256-row x 64-col swizzled f16 tile (1 issue/lane).
// linear LDS dest (wave-uniform base), inverse-swizzled global source.
__device__ __forceinline__ void stage64(f16* tile, const f16* gbase, int k0, int r0,
                                        int w, int lane) {
    const f16* src = gbase + (size_t)(r0 + w * 8 + (lane >> 3)) * EMBED + k0 +
                     (((lane & 7) ^ (lane >> 3)) << 3);
    gld_lds16(src, tile + (r0 + w * 8) * 64);
}

__global__ __launch_bounds__(256) void zero_kernel(float* __restrict__ p, int n) {
    int i = blockIdx.x * 256 + threadIdx.x;
    if (i < n) p[i] = 0.f;
}

__global__ __launch_bounds__(256) void cvt_x(const float* __restrict__ x, f16* __restrict__ xh) {
    size_t i4 = (size_t)blockIdx.x * 256 + threadIdx.x;
    float4 f = *(const float4*)&x[i4 * 4];
    f16x4 h = {(f16)f.x, (f16)f.y, (f16)f.z, (f16)f.w};
    *(f16x4*)&xh[i4 * 4] = h;
}

__global__ __launch_bounds__(256) void pack_w(
    const float* __restrict__ Wq, const float* __restrict__ Wk,
    const float* __restrict__ Wv, const float* __restrict__ Wc,
    const float* __restrict__ bq, const float* __restrict__ bk,
    const float* __restrict__ bv, const float* __restrict__ bc,
    f16* __restrict__ Wall, float* __restrict__ ball)
{
    int i4 = blockIdx.x * 256 + threadIdx.x;
    int cls = i4 >> 18;
    const float* W = cls == 0 ? Wq : cls == 1 ? Wk : cls == 2 ? Wv : Wc;
    int off = (i4 & 0x3FFFF) * 4;
    float4 f = *(const float4*)&W[off];
    f16x4 h = {(f16)f.x, (f16)f.y, (f16)f.z, (f16)f.w};
    *(f16x4*)&Wall[(size_t)i4 * 4] = h;
    if (i4 < 4096) {
        int c2 = i4 >> 10;
        const float* bb = c2 == 0 ? bq : c2 == 1 ? bk : c2 == 2 ? bv : bc;
        ball[i4] = bb[i4 & 1023];
    }
}

// ===========================================================================
// 256x256-tile phase-split GEMM main loop (shared by both GEMMs via macro).
// 512 thr = 8 waves (2 Mx4 N), per-wave 128x64 out, BK=64, dbuf LDS 128KB.
// 4 phases/K-tile: each = {stage half-tile, ds_read quadrant, setprio MFMA x16,
// barrier}; single counted vmcnt(2) per K-tile (phase 1), never 0 in-loop.
// ===========================================================================
#define GEMM256_MAINLOOP(AB, BB)                                               \
    f32x4 acc[8][4];                                                           \
    _Pragma("unroll") for (int i = 0; i < 8; ++i)                              \
        _Pragma("unroll") for (int j = 0; j < 4; ++j)                          \
            acc[i][j] = (f32x4){0.f, 0.f, 0.f, 0.f};                           \
    _Pragma("unroll") for (int r0 = 0; r0 < 256; r0 += 64)                     \
        stage64(As[0], AB, 0, r0, w, lane);                                    \
    _Pragma("unroll") for (int r0 = 0; r0 < 256; r0 += 64)                     \
        stage64(Bs[0], BB, 0, r0, w, lane);                                    \
    for (int kt = 0; kt < 16; ++kt) {                                          \
        const int cur = kt & 1, nxt = cur ^ 1;                                 \
        const int kn = (kt + 1) * 64;                                          \
        const f16* cA = As[cur]; const f16* cB = Bs[cur];                      \
        const bool st = (kt < 15);                                             \
        f16x8 af[4][2], bf[2][2];                                              \
        /* phase 1: stage A[0:128) next; wait cur landed; qm=0 qn=0 */         \
        if (st) {                                                              \
            stage64(As[nxt], AB, kn, 0, w, lane);                              \
            stage64(As[nxt], AB, kn, 64, w, lane);                             \
            asm volatile("s_waitcnt vmcnt(2)" ::: "memory");                   \
        } else {                                                               \
            asm volatile("s_waitcnt vmcnt(0)" ::: "memory");                   \
        }                                                                      \
        __builtin_amdgcn_s_barrier();                                          \
        _Pragma("unroll") for (int mi = 0; mi < 4; ++mi)                       \
            _Pragma("unroll") for (int kk = 0; kk < 2; ++kk)                   \
                af[mi][kk] = fragld(cA, R + mi * 16 + l15, kk * 32 + l4 * 8, 64); \
        _Pragma("unroll") for (int nj = 0; nj < 2; ++nj)                       \
            _Pragma("unroll") for (int kk = 0; kk < 2; ++kk)                   \
                bf[nj][kk] = fragld(cB, Cb + nj * 16 + l15, kk * 32 + l4 * 8, 64); \
        __builtin_amdgcn_s_setprio(1);                                         \
        _Pragma("unroll") for (int kk = 0; kk < 2; ++kk)                       \
            _Pragma("unroll") for (int mi = 0; mi < 4; ++mi)                   \
                _Pragma("unroll") for (int nj = 0; nj < 2; ++nj)               \
                    acc[mi][nj] = mfma16(af[mi][kk], bf[nj][kk], acc[mi][nj]); \
        __builtin_amdgcn_s_setprio(0);                                         \
        __builtin_amdgcn_s_barrier();                                          \
        /* phase 2: stage A[128:256); qm=0 qn=1 (reuse af) */                  \
        if (st) {                                                              \
            stage64(As[nxt], AB, kn, 128, w, lane);                            \
            stage64(As[nxt], AB, kn, 192, w, lane);                            \
        }                                                                      \
        _Pragma("unroll") for (int nj = 0; nj < 2; ++nj)                       \
            _Pragma("unroll") for (int kk = 0; kk < 2; ++kk)                   \
                bf[nj][kk] = fragld(cB, Cb + 32 + nj * 16 + l15, kk * 32 + l4 * 8, 64); \
        __builtin_amdgcn_s_setprio(1);                                         \
        _Pragma("unroll") for (int kk = 0; kk < 2; ++kk)                       \
            _Pragma("unroll") for (int mi = 0; mi < 4; ++mi)                   \
                _Pragma("unroll") for (int nj = 0; nj < 2; ++nj)               \
                    acc[mi][2 + nj] = mfma16(af[mi][kk], bf[nj][kk], acc[mi][2 + nj]); \
        __builtin_amdgcn_s_setprio(0);                                         \
        __builtin_amdgcn_s_barrier();                                          \
        /* phase 3: stage B[0:128); qm=1 qn=0 */                               \
        if (st) {                                                              \
            stage64(Bs[nxt], BB, kn, 0, w, lane);                              \
            stage64(Bs[nxt], BB, kn, 64, w, lane);                             \
        }                                                                      \
        _Pragma("unroll") for (int mi = 0; mi < 4; ++mi)                       \
            _Pragma("unroll") for (int kk = 0; kk < 2; ++kk)                   \
                af[mi][kk] = fragld(cA, R + 64 + mi * 16 + l15, kk * 32 + l4 * 8, 64); \
        _Pragma("unroll") for (int nj = 0; nj < 2; ++nj)                       \
            _Pragma("unroll") for (int kk = 0; kk < 2; ++kk)                   \
                bf[nj][kk] = fragld(cB, Cb + nj * 16 + l15, kk * 32 + l4 * 8, 64); \
        __builtin_amdgcn_s_setprio(1);                                         \
        _Pragma("unroll") for (int kk = 0; kk < 2; ++kk)                       \
            _Pragma("unroll") for (int mi = 0; mi < 4; ++mi)                   \
                _Pragma("unroll") for (int nj = 0; nj < 2; ++nj)               \
                    acc[4 + mi][nj] = mfma16(af[mi][kk], bf[nj][kk], acc[4 + mi][nj]); \
        __builtin_amdgcn_s_setprio(0);                                         \
        __builtin_amdgcn_s_barrier();                                          \
        /* phase 4: stage B[128:256); qm=1 qn=1 (reuse af) */                  \
        if (st) {                                                              \
            stage64(Bs[nxt], BB, kn, 128, w, lane);                            \
            stage64(Bs[nxt], BB, kn, 192, w, lane);                            \
        }                                                                      \
        _Pragma("unroll") for (int nj = 0; nj < 2; ++nj)                       \
            _Pragma("unroll") for (int kk = 0; kk < 2; ++kk)                   \
                bf[nj][kk] = fragld(cB, Cb + 32 + nj * 16 + l15, kk * 32 + l4 * 8, 64); \
        __builtin_amdgcn_s_setprio(1);                                         \
        _Pragma("unroll") for (int kk = 0; kk < 2; ++kk)                       \
            _Pragma("unroll") for (int mi = 0; mi < 4; ++mi)                   \
                _Pragma("unroll") for (int nj = 0; nj < 2; ++nj)               \
                    acc[4 + mi][2 + nj] = mfma16(af[mi][kk], bf[nj][kk], acc[4 + mi][2 + nj]); \
        __builtin_amdgcn_s_setprio(0);                                         \
        __builtin_amdgcn_s_barrier();                                          \
    }

// ---------------------------------------------------------------------------
// gemm_qkv256: C[16384,3072] = xh @ Wall[0:3072]^T; class epilogues.
// ---------------------------------------------------------------------------
__global__ __launch_bounds__(512) void gemm_qkv256(
    const f16* __restrict__ xh, const f16* __restrict__ Wall,
    const float* __restrict__ ball,
    f16* __restrict__ q, f16* __restrict__ kT, f16* __restrict__ vT)
{
    __shared__ __align__(16) f16 As[2][256 * 64];
    __shared__ __align__(16) f16 Bs[2][256 * 64];

    const int tid = threadIdx.x, lane = tid & 63, w = tid >> 6;
    const int wr = w >> 2, wc = w & 3;
    const int l15 = lane & 15, l4 = lane >> 4;
    const int R = wr * 128, Cb = wc * 64;

    // bijective XCD swizzle over 768 wgs (768 % 8 == 0)
    const int orig = blockIdx.x;
    const int wg = (orig & 7) * 96 + (orig >> 3);
    const int m0 = (wg & 63) * 256;
    const int n0 = (wg >> 6) * 256;
    const int cls = n0 >> 10;

    const f16* Ab = xh + (size_t)m0 * EMBED;
    const f16* Bb = Wall + (size_t)n0 * EMBED;

    GEMM256_MAINLOOP(Ab, Bb)

    if (cls == 0) {
        #pragma unroll
        for (int nj = 0; nj < 4; ++nj) {
            int c = n0 + Cb + nj * 16 + l15;
            float bj = ball[c];
            #pragma unroll
            for (int mi = 0; mi < 8; ++mi) {
                #pragma unroll
                for (int r = 0; r < 4; ++r) {
                    int t = m0 + R + mi * 16 + l4 * 4 + r;
                    q[(size_t)t * EMBED + c] = (f16)elu1(acc[mi][nj][r] + bj);
                }
            }
        }
    } else {
        f16* dst = (cls == 1) ? kT : vT;
        const bool act = (cls == 1);
        #pragma unroll
        for (int nj = 0; nj < 4; ++nj) {
            int n = n0 + Cb + nj * 16 + l15;
            int d = n & 1023;
            float bj = ball[n];
            #pragma unroll
            for (int mi = 0; mi < 8; ++mi) {
                int t = m0 + R + mi * 16 + l4 * 4;
                f16x4 hv;
                #pragma unroll
                for (int r = 0; r < 4; ++r) {
                    float v = acc[mi][nj][r] + bj;
                    if (act) v = elu1(v);
                    hv[r] = (f16)v;
                }
                *(f16x4*)&dst[(size_t)d * MROWS + t] = hv;
            }
        }
    }
}

// ---------------------------------------------------------------------------
// gemm_out256: out[16384,1024] = y @ Wc^T + bc (Wc = Wall rows 3072+), fp32.
// ---------------------------------------------------------------------------
__global__ __launch_bounds__(512) void gemm_out256(
    const f16* __restrict__ y, const f16* __restrict__ Wall,
    const float* __restrict__ ball, float* __restrict__ out)
{
    __shared__ __align__(16) f16 As[2][256 * 64];
    __shared__ __align__(16) f16 Bs[2][256 * 64];

    const int tid = threadIdx.x, lane = tid & 63, w = tid >> 6;
    const int wr = w >> 2, wc = w & 3;
    const int l15 = lane & 15, l4 = lane >> 4;
    const int R = wr * 128, Cb = wc * 64;

    const int orig = blockIdx.x;                 // 256 wgs
    const int wg = (orig & 7) * 32 + (orig >> 3);
    const int m0 = (wg & 63) * 256;
    const int n0 = (wg >> 6) * 256;

    const f16* Ab = y + (size_t)m0 * EMBED;
    const f16* Bb = Wall + (size_t)(3072 + n0) * EMBED;

    GEMM256_MAINLOOP(Ab, Bb)

    #pragma unroll
    for (int nj = 0; nj < 4; ++nj) {
        int n = n0 + Cb + nj * 16 + l15;
        float bj = ball[3072 + n];
        #pragma unroll
        for (int mi = 0; mi < 8; ++mi) {
            #pragma unroll
            for (int r = 0; r < 4; ++r) {
                int m = m0 + R + mi * 16 + l4 * 4 + r;
                out[(size_t)m * EMBED + n] = acc[mi][nj][r] + bj;
            }
        }
    }
}

// ---------------------------------------------------------------------------
// kv_ksum: per (bh, 512-t chunk): kvg[e][d] += sum_t v[t,e] k[t,d] (MFMA),
// ksg[d] += sum_t k[t,d]. Inputs kT,vT are [1024 d][16384 t] f16.
// ---------------------------------------------------------------------------
__global__ __launch_bounds__(256) void kv_ksum(
    const f16* __restrict__ kT, const f16* __restrict__ vT,
    float* __restrict__ kvg, float* __restrict__ ksg)
{
    __shared__ __align__(16) f16 kl[64 * 128];
    __shared__ __align__(16) f16 vl[64 * 128];

    const int bh = blockIdx.x, b = bh >> 4, h = bh & 15;
    const int tid = threadIdx.x, lane = tid & 63, w = tid >> 6;
    const int l15 = lane & 15, l4 = lane >> 4;
    const int tbase = b * TSEQ + blockIdx.y * 512;

    f32x4 kvacc[4];
    #pragma unroll
    for (int j = 0; j < 4; ++j) kvacc[j] = (f32x4){0.f, 0.f, 0.f, 0.f};
    float ksacc = 0.f;

    for (int ss = 0; ss < 4; ++ss) {
        const int tg = tbase + ss * 128;
        #pragma unroll
        for (int c = 0; c < 4; ++c) {
            int idx = tid + c * 256;
            int row = idx >> 4, t8 = (idx & 15) << 3;
            f16x8 a = *(const f16x8*)&kT[(size_t)(h * 64 + row) * MROWS + tg + t8];
            *(f16x8*)&kl[swzc(row, t8, 128)] = a;
            f16x8 bb = *(const f16x8*)&vT[(size_t)(h * 64 + row) * MROWS + tg + t8];
            *(f16x8*)&vl[swzc(row, t8, 128)] = bb;
        }
        __syncthreads();
        #pragma unroll
        for (int kk = 0; kk < 128; kk += 32) {
            f16x8 a = fragld(vl, 16 * w + l15, kk + l4 * 8, 128);
            #pragma unroll
            for (int j = 0; j < 4; ++j) {
                f16x8 bfr = fragld(kl, j * 16 + l15, kk + l4 * 8, 128);
                kvacc[j] = mfma16(a, bfr, kvacc[j]);
            }
        }
        {
            int d = tid & 63, qq = tid >> 6;
            #pragma unroll
            for (int t8 = 0; t8 < 32; t8 += 8) {
                f16x8 kv8 = fragld(kl, d, qq * 32 + t8, 128);
                #pragma unroll
                for (int e = 0; e < 8; ++e) ksacc += (float)kv8[e];
            }
        }
        __syncthreads();
    }

    #pragma unroll
    for (int j = 0; j < 4; ++j)
        #pragma unroll
        for (int r = 0; r < 4; ++r)
            atomicAdd(&kvg[(size_t)bh * 4096 +
                           (size_t)(16 * w + l4 * 4 + r) * HD + j * 16 + l15],
                      kvacc[j][r]);
    atomicAdd(&ksg[bh * HD + (tid & 63)], ksacc);
}

// ---------------------------------------------------------------------------
// y_kernel: per (bh, 128 t): z[t]=1/(q.ks+1e-6); y[t][e]=sum_d q[t,d]kv[d,e]*z
// ---------------------------------------------------------------------------
__global__ __launch_bounds__(256) void y_kernel(
    const f16* __restrict__ q, const float* __restrict__ kvg,
    const float* __restrict__ ksg, f16* __restrict__ y)
{
    __shared__ __align__(16) f16 qs[128 * 64];
    __shared__ __align__(16) f16 kvs[64 * 64];
    __shared__ __align__(16) f16 ylds[128 * 64];
    __shared__ float kss[64];
    __shared__ float zs[128];

    const int bh = blockIdx.x, b = bh >> 4, h = bh & 15;
    const int tid = threadIdx.x, lane = tid & 63, w = tid >> 6;
    const int l15 = lane & 15, l4 = lane >> 4;
    const int t0g = b * TSEQ + blockIdx.y * 128;

    #pragma unroll
    for (int c = 0; c < 4; ++c) {
        int idx = tid + c * 256;
        int row = idx >> 3, col8 = (idx & 7) << 3;
        f16x8 v = *(const f16x8*)&q[(size_t)(t0g + row) * EMBED + h * 64 + col8];
        *(f16x8*)&qs[swzc(row, col8, 64)] = v;
    }
    #pragma unroll
    for (int c = 0; c < 4; ++c) {
        int idx = tid + c * 256;
        int e = idx >> 4, d4 = (idx & 15) << 2;
        float4 f = *(const float4*)&kvg[(size_t)bh * 4096 + e * 64 + d4];
        f16x4 hv = {(f16)f.x, (f16)f.y, (f16)f.z, (f16)f.w};
        *(f16x4*)&kvs[swzc(e, d4, 64)] = hv;
    }
    if (tid < 64) kss[tid] = ksg[bh * HD + tid];
    __syncthreads();

    {
        int t = tid >> 1, dh = (tid & 1) * 32;
        float s = 0.f;
        #pragma unroll
        for (int d8 = 0; d8 < 32; d8 += 8) {
            f16x8 qv = fragld(qs, t, dh + d8, 64);
            #pragma unroll
            for (int e = 0; e < 8; ++e) s += (float)qv[e] * kss[dh + d8 + e];
        }
        s += __shfl_xor(s, 1);
        if ((tid & 1) == 0) zs[t] = 1.f / (s + 1e-6f);
    }
    __syncthreads();

    f32x4 yacc[8];
    #pragma unroll
    for (int jn = 0; jn < 8; ++jn) yacc[jn] = (f32x4){0.f, 0.f, 0.f, 0.f};
    #pragma unroll
    for (int kk = 0; kk < 64; kk += 32) {
        f16x8 a = fragld(kvs, 16 * w + l15, kk + l4 * 8, 64);
        #pragma unroll
        for (int jn = 0; jn < 8; ++jn) {
            f16x8 bq8 = fragld(qs, jn * 16 + l15, kk + l4 * 8, 64);
            yacc[jn] = mfma16(a, bq8, yacc[jn]);
        }
    }
    #pragma unroll
    for (int jn = 0; jn < 8; ++jn) {
        int t = jn * 16 + l15;
        float z = zs[t];
        int e0 = 16 * w + l4 * 4;
        f16x4 hv;
        #pragma unroll
        for (int r = 0; r < 4; ++r) hv[r] = (f16)(yacc[jn][r] * z);
        *(f16x4*)&ylds[swzc(t, e0, 64)] = hv;
    }
    __syncthreads();

    {
        int row = tid >> 1, eh = (tid & 1) * 32;
        size_t gb = (size_t)(t0g + row) * EMBED + h * 64 + eh;
        #pragma unroll
        for (int c8 = 0; c8 < 32; c8 += 8) {
            f16x8 v = fragld(ylds, row, eh + c8, 64);
            *(f16x8*)&y[gb + c8] = v;
        }
    }
}

// ---------------------------------------------------------------------------
extern "C" void kernel_launch(void* const* d_in, const int* in_sizes, int n_in,
                              void* d_out, int out_size, void* d_ws, size_t ws_size,
                              hipStream_t stream) {
    (void)in_sizes; (void)n_in; (void)out_size; (void)ws_size;
    const float* x  = (const float*)d_in[0];
    const float* Wq = (const float*)d_in[1];
    const float* bq = (const float*)d_in[2];
    const float* Wk = (const float*)d_in[3];
    const float* bk = (const float*)d_in[4];
    const float* Wv = (const float*)d_in[5];
    const float* bv = (const float*)d_in[6];
    const float* Wc = (const float*)d_in[7];
    const float* bc = (const float*)d_in[8];
    float* out = (float*)d_out;

    char* W = (char*)d_ws;
    f16* xh   = (f16*)W;
    f16* q_ws = (f16*)(W + 33554432);
    f16* kT   = (f16*)(W + 67108864);
    f16* vT   = (f16*)(W + 100663296);
    f16* Wall = (f16*)(W + 134217728);
    float* ball = (float*)(W + 142606336);
    float* kvg  = (float*)(W + 142622720);
    float* ksg  = (float*)(W + 143671296);

    cvt_x<<<16384, 256, 0, stream>>>(x, xh);
    pack_w<<<4096, 256, 0, stream>>>(Wq, Wk, Wv, Wc, bq, bk, bv, bc, Wall, ball);

    const int nzero = BH * HD * HD + BH * HD;
    zero_kernel<<<(nzero + 255) / 256, 256, 0, stream>>>(kvg, nzero);

    gemm_qkv256<<<768, 512, 0, stream>>>(xh, Wall, ball, q_ws, kT, vT);

    kv_ksum<<<dim3(BH, 8), 256, 0, stream>>>(kT, vT, kvg, ksg);

    y_kernel<<<dim3(BH, TSEQ / 128), 256, 0, stream>>>(q_ws, kvg, ksg, q_ws);

    gemm_out256<<<256, 512, 0, stream>>>(q_ws, Wall, ball, out);
}

// Round 7
// 258.055 us; speedup vs baseline: 1.1146x; 1.1146x over previous
//
#include <hip/hip_runtime.h>
#include <math.h>

#define EMBED 1024
#define HEADS 16
#define HD 64
#define BATCH 4
#define TSEQ 4096
#define BH (BATCH * HEADS)
#define MROWS (BATCH * TSEQ)   // 16384

typedef _Float16 f16;
typedef __attribute__((ext_vector_type(4))) _Float16 f16x4;
typedef __attribute__((ext_vector_type(8))) _Float16 f16x8;
typedef __attribute__((ext_vector_type(4))) float f32x4;

#define GLOBAL_AS __attribute__((address_space(1)))
#define LDS_AS __attribute__((address_space(3)))

__device__ __forceinline__ float elu1(float v) {
    return v > 0.f ? v + 1.f : __expf(v);
}

// XOR-swizzled element offset in a [rows][cols] f16 tile; 16B granules.
__device__ __forceinline__ int swzc(int row, int col, int cols) {
    int g = (col >> 3) ^ (row & 7);
    return row * cols + (g << 3) + (col & 7);
}

__device__ __forceinline__ f16x8 fragld(const f16* t, int row, int k, int cols) {
    return *(const f16x8*)&t[swzc(row, k, cols)];
}

__device__ __forceinline__ f32x4 mfma16(f16x8 a, f16x8 b, f32x4 c) {
    return __builtin_amdgcn_mfma_f32_16x16x32_f16(a, b, c, 0, 0, 0);
}

__device__ __forceinline__ void gld_lds16(const f16* g, f16* l) {
    __builtin_amdgcn_global_load_lds((const GLOBAL_AS void*)g, (LDS_AS void*)l, 16, 0, 0);
}

// stage rows [r0, r0+64) of a 256-row x 64-col swizzled f16 tile (1 issue/lane).
// linear LDS dest (wave-uniform base), inverse-swizzled global source.
__device__ __forceinline__ void stage64(f16* tile, const f16* gbase, int k0, int r0,
                                        int w, int lane) {
    const f16* src = gbase + (size_t)(r0 + w * 8 + (lane >> 3)) * EMBED + k0 +
                     (((lane & 7) ^ (lane >> 3)) << 3);
    gld_lds16(src, tile + (r0 + w * 8) * 64);
}

__global__ __launch_bounds__(256) void zero_kernel(float* __restrict__ p, int n) {
    int i = blockIdx.x * 256 + threadIdx.x;
    if (i < n) p[i] = 0.f;
}

__global__ __launch_bounds__(256) void cvt_x(const float* __restrict__ x, f16* __restrict__ xh) {
    size_t i4 = (size_t)blockIdx.x * 256 + threadIdx.x;
    float4 f = *(const float4*)&x[i4 * 4];
    f16x4 h = {(f16)f.x, (f16)f.y, (f16)f.z, (f16)f.w};
    *(f16x4*)&xh[i4 * 4] = h;
}

__global__ __launch_bounds__(256) void pack_w(
    const float* __restrict__ Wq, const float* __restrict__ Wk,
    const float* __restrict__ Wv, const float* __restrict__ Wc,
    const float* __restrict__ bq, const float* __restrict__ bk,
    const float* __restrict__ bv, const float* __restrict__ bc,
    f16* __restrict__ Wall, float* __restrict__ ball)
{
    int i4 = blockIdx.x * 256 + threadIdx.x;
    int cls = i4 >> 18;
    const float* W = cls == 0 ? Wq : cls == 1 ? Wk : cls == 2 ? Wv : Wc;
    int off = (i4 & 0x3FFFF) * 4;
    float4 f = *(const float4*)&W[off];
    f16x4 h = {(f16)f.x, (f16)f.y, (f16)f.z, (f16)f.w};
    *(f16x4*)&Wall[(size_t)i4 * 4] = h;
    if (i4 < 4096) {
        int c2 = i4 >> 10;
        const float* bb = c2 == 0 ? bq : c2 == 1 ? bk : c2 == 2 ? bv : bc;
        ball[i4] = bb[i4 & 1023];
    }
}

// ===========================================================================
// 256x256-tile phase-split GEMM main loop. 512 thr = 8 waves (2M x 4N),
// per-wave 128x64 out, BK=64, dbuf LDS 128KB.
// Staging: ALL of next A at phase 1 (4 loads/lane), all of next B at phase 2.
// Wait: vmcnt(4) at phase 1 -> certifies current buffer (issued 3-4 phases
// ago, ~480-640cyc slack). Phases 3-4: compute only. Never vmcnt(0) in-loop.
// ===========================================================================
#define FENCE() asm volatile("" ::: "memory")

#define GEMM256_MAINLOOP(AB, BB)                                               \
    f32x4 acc[8][4];                                                           \
    _Pragma("unroll") for (int i = 0; i < 8; ++i)                              \
        _Pragma("unroll") for (int j = 0; j < 4; ++j)                          \
            acc[i][j] = (f32x4){0.f, 0.f, 0.f, 0.f};                           \
    _Pragma("unroll") for (int r0 = 0; r0 < 256; r0 += 64)                     \
        stage64(As[0], AB, 0, r0, w, lane);                                    \
    _Pragma("unroll") for (int r0 = 0; r0 < 256; r0 += 64)                     \
        stage64(Bs[0], BB, 0, r0, w, lane);                                    \
    for (int kt = 0; kt < 16; ++kt) {                                          \
        const int cur = kt & 1, nxt = cur ^ 1;                                 \
        const int kn = (kt + 1) * 64;                                          \
        const f16* cA = As[cur]; const f16* cB = Bs[cur];                      \
        const bool st = (kt < 15);                                             \
        f16x8 af[4][2], bf[2][2];                                              \
        /* ---- phase 1: stage next-A (whole), certify cur, C[0:64)x[0:32) */  \
        if (st) {                                                              \
            stage64(As[nxt], AB, kn, 0, w, lane);                              \
            stage64(As[nxt], AB, kn, 64, w, lane);                             \
            stage64(As[nxt], AB, kn, 128, w, lane);                            \
            stage64(As[nxt], AB, kn, 192, w, lane);                            \
            asm volatile("s_waitcnt vmcnt(4)" ::: "memory");                   \
        } else {                                                               \
            asm volatile("s_waitcnt vmcnt(0)" ::: "memory");                   \
        }                                                                      \
        __builtin_amdgcn_s_barrier();                                          \
        FENCE();                                                               \
        _Pragma("unroll") for (int mi = 0; mi < 4; ++mi)                       \
            _Pragma("unroll") for (int kk = 0; kk < 2; ++kk)                   \
                af[mi][kk] = fragld(cA, R + mi * 16 + l15, kk * 32 + l4 * 8, 64); \
        _Pragma("unroll") for (int nj = 0; nj < 2; ++nj)                       \
            _Pragma("unroll") for (int kk = 0; kk < 2; ++kk)                   \
                bf[nj][kk] = fragld(cB, Cb + nj * 16 + l15, kk * 32 + l4 * 8, 64); \
        __builtin_amdgcn_s_setprio(1);                                         \
        _Pragma("unroll") for (int kk = 0; kk < 2; ++kk)                       \
            _Pragma("unroll") for (int mi = 0; mi < 4; ++mi)                   \
                _Pragma("unroll") for (int nj = 0; nj < 2; ++nj)               \
                    acc[mi][nj] = mfma16(af[mi][kk], bf[nj][kk], acc[mi][nj]); \
        __builtin_amdgcn_s_setprio(0);                                         \
        __builtin_amdgcn_s_barrier();                                          \
        FENCE();                                                               \
        /* ---- phase 2: stage next-B (whole), C[0:64)x[32:64) */              \
        if (st) {                                                              \
            stage64(Bs[nxt], BB, kn, 0, w, lane);                              \
            stage64(Bs[nxt], BB, kn, 64, w, lane);                             \
            stage64(Bs[nxt], BB, kn, 128, w, lane);                            \
            stage64(Bs[nxt], BB, kn, 192, w, lane);                            \
        }                                                                      \
        _Pragma("unroll") for (int nj = 0; nj < 2; ++nj)                       \
            _Pragma("unroll") for (int kk = 0; kk < 2; ++kk)                   \
                bf[nj][kk] = fragld(cB, Cb + 32 + nj * 16 + l15, kk * 32 + l4 * 8, 64); \
        __builtin_amdgcn_s_setprio(1);                                         \
        _Pragma("unroll") for (int kk = 0; kk < 2; ++kk)                       \
            _Pragma("unroll") for (int mi = 0; mi < 4; ++mi)                   \
                _Pragma("unroll") for (int nj = 0; nj < 2; ++nj)               \
                    acc[mi][2 + nj] = mfma16(af[mi][kk], bf[nj][kk], acc[mi][2 + nj]); \
        __builtin_amdgcn_s_setprio(0);                                         \
        __builtin_amdgcn_s_barrier();                                          \
        FENCE();                                                               \
        /* ---- phase 3: C[64:128)x[0:32) */                                  \
        _Pragma("unroll") for (int mi = 0; mi < 4; ++mi)                       \
            _Pragma("unroll") for (int kk = 0; kk < 2; ++kk)                   \
                af[mi][kk] = fragld(cA, R + 64 + mi * 16 + l15, kk * 32 + l4 * 8, 64); \
        _Pragma("unroll") for (int nj = 0; nj < 2; ++nj)                       \
            _Pragma("unroll") for (int kk = 0; kk < 2; ++kk)                   \
                bf[nj][kk] = fragld(cB, Cb + nj * 16 + l15, kk * 32 + l4 * 8, 64); \
        __builtin_amdgcn_s_setprio(1);                                         \
        _Pragma("unroll") for (int kk = 0; kk < 2; ++kk)                       \
            _Pragma("unroll") for (int mi = 0; mi < 4; ++mi)                   \
                _Pragma("unroll") for (int nj = 0; nj < 2; ++nj)               \
                    acc[4 + mi][nj] = mfma16(af[mi][kk], bf[nj][kk], acc[4 + mi][nj]); \
        __builtin_amdgcn_s_setprio(0);                                         \
        __builtin_amdgcn_s_barrier();                                          \
        FENCE();                                                               \
        /* ---- phase 4: C[64:128)x[32:64) */                                 \
        _Pragma("unroll") for (int nj = 0; nj < 2; ++nj)                       \
            _Pragma("unroll") for (int kk = 0; kk < 2; ++kk)                   \
                bf[nj][kk] = fragld(cB, Cb + 32 + nj * 16 + l15, kk * 32 + l4 * 8, 64); \
        __builtin_amdgcn_s_setprio(1);                                         \
        _Pragma("unroll") for (int kk = 0; kk < 2; ++kk)                       \
            _Pragma("unroll") for (int mi = 0; mi < 4; ++mi)                   \
                _Pragma("unroll") for (int nj = 0; nj < 2; ++nj)               \
                    acc[4 + mi][2 + nj] = mfma16(af[mi][kk], bf[nj][kk], acc[4 + mi][2 + nj]); \
        __builtin_amdgcn_s_setprio(0);                                         \
        __builtin_amdgcn_s_barrier();                                          \
        FENCE();                                                               \
    }

// ---------------------------------------------------------------------------
// gemm_qkv256: C[16384,3072] = xh @ Wall[0:3072]^T; class epilogues.
// Raster: each XCD owns 8 m-tiles x all 12 n-tiles (A set 4MB ~= L2).
// ---------------------------------------------------------------------------
__global__ __launch_bounds__(512) void gemm_qkv256(
    const f16* __restrict__ xh, const f16* __restrict__ Wall,
    const float* __restrict__ ball,
    f16* __restrict__ q, f16* __restrict__ kT, f16* __restrict__ vT)
{
    __shared__ __align__(16) f16 As[2][256 * 64];
    __shared__ __align__(16) f16 Bs[2][256 * 64];

    const int tid = threadIdx.x, lane = tid & 63, w = tid >> 6;
    const int wr = w >> 2, wc = w & 3;
    const int l15 = lane & 15, l4 = lane >> 4;
    const int R = wr * 128, Cb = wc * 64;

    // bijective: 768 = 8 xcd * 12 n * 8 mloc
    const int orig = blockIdx.x;
    const int xcd = orig & 7;
    const int local = orig >> 3;          // 0..95
    const int ntile = local >> 3;         // 0..11
    const int mloc = local & 7;
    const int m0 = (xcd * 8 + mloc) * 256;
    const int n0 = ntile * 256;
    const int cls = n0 >> 10;

    const f16* Ab = xh + (size_t)m0 * EMBED;
    const f16* Bb = Wall + (size_t)n0 * EMBED;

    GEMM256_MAINLOOP(Ab, Bb)

    if (cls == 0) {
        #pragma unroll
        for (int nj = 0; nj < 4; ++nj) {
            int c = n0 + Cb + nj * 16 + l15;
            float bj = ball[c];
            #pragma unroll
            for (int mi = 0; mi < 8; ++mi) {
                #pragma unroll
                for (int r = 0; r < 4; ++r) {
                    int t = m0 + R + mi * 16 + l4 * 4 + r;
                    q[(size_t)t * EMBED + c] = (f16)elu1(acc[mi][nj][r] + bj);
                }
            }
        }
    } else {
        f16* dst = (cls == 1) ? kT : vT;
        const bool act = (cls == 1);
        #pragma unroll
        for (int nj = 0; nj < 4; ++nj) {
            int n = n0 + Cb + nj * 16 + l15;
            int d = n & 1023;
            float bj = ball[n];
            #pragma unroll
            for (int mi = 0; mi < 8; ++mi) {
                int t = m0 + R + mi * 16 + l4 * 4;
                f16x4 hv;
                #pragma unroll
                for (int r = 0; r < 4; ++r) {
                    float v = acc[mi][nj][r] + bj;
                    if (act) v = elu1(v);
                    hv[r] = (f16)v;
                }
                *(f16x4*)&dst[(size_t)d * MROWS + t] = hv;
            }
        }
    }
}

// ---------------------------------------------------------------------------
// gemm_out256: out[16384,1024] = y @ Wc^T + bc (Wc = Wall rows 3072+), fp32.
// ---------------------------------------------------------------------------
__global__ __launch_bounds__(512) void gemm_out256(
    const f16* __restrict__ y, const f16* __restrict__ Wall,
    const float* __restrict__ ball, float* __restrict__ out)
{
    __shared__ __align__(16) f16 As[2][256 * 64];
    __shared__ __align__(16) f16 Bs[2][256 * 64];

    const int tid = threadIdx.x, lane = tid & 63, w = tid >> 6;
    const int wr = w >> 2, wc = w & 3;
    const int l15 = lane & 15, l4 = lane >> 4;
    const int R = wr * 128, Cb = wc * 64;

    // bijective: 256 = 8 xcd * 4 n * 8 mloc
    const int orig = blockIdx.x;
    const int xcd = orig & 7;
    const int local = orig >> 3;          // 0..31
    const int ntile = local >> 3;         // 0..3
    const int mloc = local & 7;
    const int m0 = (xcd * 8 + mloc) * 256;
    const int n0 = ntile * 256;

    const f16* Ab = y + (size_t)m0 * EMBED;
    const f16* Bb = Wall + (size_t)(3072 + n0) * EMBED;

    GEMM256_MAINLOOP(Ab, Bb)

    #pragma unroll
    for (int nj = 0; nj < 4; ++nj) {
        int n = n0 + Cb + nj * 16 + l15;
        float bj = ball[3072 + n];
        #pragma unroll
        for (int mi = 0; mi < 8; ++mi) {
            #pragma unroll
            for (int r = 0; r < 4; ++r) {
                int m = m0 + R + mi * 16 + l4 * 4 + r;
                out[(size_t)m * EMBED + n] = acc[mi][nj][r] + bj;
            }
        }
    }
}

// ---------------------------------------------------------------------------
// kv_ksum: per (bh, 512-t chunk): kvg[e][d] += sum_t v[t,e] k[t,d] (MFMA),
// ksg[d] += sum_t k[t,d]. Inputs kT,vT are [1024 d][16384 t] f16.
// ---------------------------------------------------------------------------
__global__ __launch_bounds__(256) void kv_ksum(
    const f16* __restrict__ kT, const f16* __restrict__ vT,
    float* __restrict__ kvg, float* __restrict__ ksg)
{
    __shared__ __align__(16) f16 kl[64 * 128];
    __shared__ __align__(16) f16 vl[64 * 128];

    const int bh = blockIdx.x, b = bh >> 4, h = bh & 15;
    const int tid = threadIdx.x, lane = tid & 63, w = tid >> 6;
    const int l15 = lane & 15, l4 = lane >> 4;
    const int tbase = b * TSEQ + blockIdx.y * 512;

    f32x4 kvacc[4];
    #pragma unroll
    for (int j = 0; j < 4; ++j) kvacc[j] = (f32x4){0.f, 0.f, 0.f, 0.f};
    float ksacc = 0.f;

    for (int ss = 0; ss < 4; ++ss) {
        const int tg = tbase + ss * 128;
        #pragma unroll
        for (int c = 0; c < 4; ++c) {
            int idx = tid + c * 256;
            int row = idx >> 4, t8 = (idx & 15) << 3;
            f16x8 a = *(const f16x8*)&kT[(size_t)(h * 64 + row) * MROWS + tg + t8];
            *(f16x8*)&kl[swzc(row, t8, 128)] = a;
            f16x8 bb = *(const f16x8*)&vT[(size_t)(h * 64 + row) * MROWS + tg + t8];
            *(f16x8*)&vl[swzc(row, t8, 128)] = bb;
        }
        __syncthreads();
        #pragma unroll
        for (int kk = 0; kk < 128; kk += 32) {
            f16x8 a = fragld(vl, 16 * w + l15, kk + l4 * 8, 128);
            #pragma unroll
            for (int j = 0; j < 4; ++j) {
                f16x8 bfr = fragld(kl, j * 16 + l15, kk + l4 * 8, 128);
                kvacc[j] = mfma16(a, bfr, kvacc[j]);
            }
        }
        {
            int d = tid & 63, qq = tid >> 6;
            #pragma unroll
            for (int t8 = 0; t8 < 32; t8 += 8) {
                f16x8 kv8 = fragld(kl, d, qq * 32 + t8, 128);
                #pragma unroll
                for (int e = 0; e < 8; ++e) ksacc += (float)kv8[e];
            }
        }
        __syncthreads();
    }

    #pragma unroll
    for (int j = 0; j < 4; ++j)
        #pragma unroll
        for (int r = 0; r < 4; ++r)
            atomicAdd(&kvg[(size_t)bh * 4096 +
                           (size_t)(16 * w + l4 * 4 + r) * HD + j * 16 + l15],
                      kvacc[j][r]);
    atomicAdd(&ksg[bh * HD + (tid & 63)], ksacc);
}

// ---------------------------------------------------------------------------
// y_kernel: per (bh, 128 t): z[t]=1/(q.ks+1e-6); y[t][e]=sum_d q[t,d]kv[d,e]*z
// ---------------------------------------------------------------------------
__global__ __launch_bounds__(256) void y_kernel(
    const f16* __restrict__ q, const float* __restrict__ kvg,
    const float* __restrict__ ksg, f16* __restrict__ y)
{
    __shared__ __align__(16) f16 qs[128 * 64];
    __shared__ __align__(16) f16 kvs[64 * 64];
    __shared__ __align__(16) f16 ylds[128 * 64];
    __shared__ float kss[64];
    __shared__ float zs[128];

    const int bh = blockIdx.x, b = bh >> 4, h = bh & 15;
    const int tid = threadIdx.x, lane = tid & 63, w = tid >> 6;
    const int l15 = lane & 15, l4 = lane >> 4;
    const int t0g = b * TSEQ + blockIdx.y * 128;

    #pragma unroll
    for (int c = 0; c < 4; ++c) {
        int idx = tid + c * 256;
        int row = idx >> 3, col8 = (idx & 7) << 3;
        f16x8 v = *(const f16x8*)&q[(size_t)(t0g + row) * EMBED + h * 64 + col8];
        *(f16x8*)&qs[swzc(row, col8, 64)] = v;
    }
    #pragma unroll
    for (int c = 0; c < 4; ++c) {
        int idx = tid + c * 256;
        int e = idx >> 4, d4 = (idx & 15) << 2;
        float4 f = *(const float4*)&kvg[(size_t)bh * 4096 + e * 64 + d4];
        f16x4 hv = {(f16)f.x, (f16)f.y, (f16)f.z, (f16)f.w};
        *(f16x4*)&kvs[swzc(e, d4, 64)] = hv;
    }
    if (tid < 64) kss[tid] = ksg[bh * HD + tid];
    __syncthreads();

    {
        int t = tid >> 1, dh = (tid & 1) * 32;
        float s = 0.f;
        #pragma unroll
        for (int d8 = 0; d8 < 32; d8 += 8) {
            f16x8 qv = fragld(qs, t, dh + d8, 64);
            #pragma unroll
            for (int e = 0; e < 8; ++e) s += (float)qv[e] * kss[dh + d8 + e];
        }
        s += __shfl_xor(s, 1);
        if ((tid & 1) == 0) zs[t] = 1.f / (s + 1e-6f);
    }
    __syncthreads();

    f32x4 yacc[8];
    #pragma unroll
    for (int jn = 0; jn < 8; ++jn) yacc[jn] = (f32x4){0.f, 0.f, 0.f, 0.f};
    #pragma unroll
    for (int kk = 0; kk < 64; kk += 32) {
        f16x8 a = fragld(kvs, 16 * w + l15, kk + l4 * 8, 64);
        #pragma unroll
        for (int jn = 0; jn < 8; ++jn) {
            f16x8 bq8 = fragld(qs, jn * 16 + l15, kk + l4 * 8, 64);
            yacc[jn] = mfma16(a, bq8, yacc[jn]);
        }
    }
    #pragma unroll
    for (int jn = 0; jn < 8; ++jn) {
        int t = jn * 16 + l15;
        float z = zs[t];
        int e0 = 16 * w + l4 * 4;
        f16x4 hv;
        #pragma unroll
        for (int r = 0; r < 4; ++r) hv[r] = (f16)(yacc[jn][r] * z);
        *(f16x4*)&ylds[swzc(t, e0, 64)] = hv;
    }
    __syncthreads();

    {
        int row = tid >> 1, eh = (tid & 1) * 32;
        size_t gb = (size_t)(t0g + row) * EMBED + h * 64 + eh;
        #pragma unroll
        for (int c8 = 0; c8 < 32; c8 += 8) {
            f16x8 v = fragld(ylds, row, eh + c8, 64);
            *(f16x8*)&y[gb + c8] = v;
        }
    }
}

// ---------------------------------------------------------------------------
extern "C" void kernel_launch(void* const* d_in, const int* in_sizes, int n_in,
                              void* d_out, int out_size, void* d_ws, size_t ws_size,
                              hipStream_t stream) {
    (void)in_sizes; (void)n_in; (void)out_size; (void)ws_size;
    const float* x  = (const float*)d_in[0];
    const float* Wq = (const float*)d_in[1];
    const float* bq = (const float*)d_in[2];
    const float* Wk = (const float*)d_in[3];
    const float* bk = (const float*)d_in[4];
    const float* Wv = (const float*)d_in[5];
    const float* bv = (const float*)d_in[6];
    const float* Wc = (const float*)d_in[7];
    const float* bc = (const float*)d_in[8];
    float* out = (float*)d_out;

    char* W = (char*)d_ws;
    f16* xh   = (f16*)W;
    f16* q_ws = (f16*)(W + 33554432);
    f16* kT   = (f16*)(W + 67108864);
    f16* vT   = (f16*)(W + 100663296);
    f16* Wall = (f16*)(W + 134217728);
    float* ball = (float*)(W + 142606336);
    float* kvg  = (float*)(W + 142622720);
    float* ksg  = (float*)(W + 143671296);

    cvt_x<<<16384, 256, 0, stream>>>(x, xh);
    pack_w<<<4096, 256, 0, stream>>>(Wq, Wk, Wv, Wc, bq, bk, bv, bc, Wall, ball);

    const int nzero = BH * HD * HD + BH * HD;
    zero_kernel<<<(nzero + 255) / 256, 256, 0, stream>>>(kvg, nzero);

    gemm_qkv256<<<768, 512, 0, stream>>>(xh, Wall, ball, q_ws, kT, vT);

    kv_ksum<<<dim3(BH, 8), 256, 0, stream>>>(kT, vT, kvg, ksg);

    y_kernel<<<dim3(BH, TSEQ / 128), 256, 0, stream>>>(q_ws, kvg, ksg, q_ws);

    gemm_out256<<<256, 512, 0, stream>>>(q_ws, Wall, ball, out);
}

// Round 8
// 256.404 us; speedup vs baseline: 1.1218x; 1.0064x over previous
//
#include <hip/hip_runtime.h>
#include <math.h>

#define EMBED 1024
#define HEADS 16
#define HD 64
#define BATCH 4
#define TSEQ 4096
#define BH (BATCH * HEADS)
#define MROWS (BATCH * TSEQ)   // 16384

typedef _Float16 f16;
typedef __attribute__((ext_vector_type(4))) _Float16 f16x4;
typedef __attribute__((ext_vector_type(8))) _Float16 f16x8;
typedef __attribute__((ext_vector_type(4))) float f32x4;

#define GLOBAL_AS __attribute__((address_space(1)))
#define LDS_AS __attribute__((address_space(3)))

__device__ __forceinline__ float elu1(float v) {
    return v > 0.f ? v + 1.f : __expf(v);
}

// XOR-swizzled element offset in a [rows][cols] f16 tile; 16B granules.
__device__ __forceinline__ int swzc(int row, int col, int cols) {
    int g = (col >> 3) ^ (row & 7);
    return row * cols + (g << 3) + (col & 7);
}

__device__ __forceinline__ f16x8 fragld(const f16* t, int row, int k, int cols) {
    return *(const f16x8*)&t[swzc(row, k, cols)];
}

__device__ __forceinline__ f32x4 mfma16(f16x8 a, f16x8 b, f32x4 c) {
    return __builtin_amdgcn_mfma_f32_16x16x32_f16(a, b, c, 0, 0, 0);
}

__device__ __forceinline__ void gld_lds16(const f16* g, f16* l) {
    __builtin_amdgcn_global_load_lds((const GLOBAL_AS void*)g, (LDS_AS void*)l, 16, 0, 0);
}

// stage rows [r0, r0+64) of a 256-row x 64-col swizzled f16 tile (1 issue/lane,
// 512 threads). linear LDS dest (wave-uniform base), inverse-swizzled source.
__device__ __forceinline__ void stage64(f16* tile, const f16* gbase, int k0, int r0,
                                        int w, int lane) {
    const f16* src = gbase + (size_t)(r0 + w * 8 + (lane >> 3)) * EMBED + k0 +
                     (((lane & 7) ^ (lane >> 3)) << 3);
    gld_lds16(src, tile + (r0 + w * 8) * 64);
}

#define FENCE() asm volatile("" ::: "memory")

__global__ __launch_bounds__(256) void cvt_x(const float* __restrict__ x, f16* __restrict__ xh) {
    size_t i4 = (size_t)blockIdx.x * 256 + threadIdx.x;
    float4 f = *(const float4*)&x[i4 * 4];
    f16x4 h = {(f16)f.x, (f16)f.y, (f16)f.z, (f16)f.w};
    *(f16x4*)&xh[i4 * 4] = h;
}

// pack weights -> Wall f16, biases -> ball; also zero kv/ks accumulators.
__global__ __launch_bounds__(256) void pack_w(
    const float* __restrict__ Wq, const float* __restrict__ Wk,
    const float* __restrict__ Wv, const float* __restrict__ Wc,
    const float* __restrict__ bq, const float* __restrict__ bk,
    const float* __restrict__ bv, const float* __restrict__ bc,
    f16* __restrict__ Wall, float* __restrict__ ball, float* __restrict__ kvz)
{
    int i4 = blockIdx.x * 256 + threadIdx.x;           // < 1048576
    int cls = i4 >> 18;
    const float* W = cls == 0 ? Wq : cls == 1 ? Wk : cls == 2 ? Wv : Wc;
    int off = (i4 & 0x3FFFF) * 4;
    float4 f = *(const float4*)&W[off];
    f16x4 h = {(f16)f.x, (f16)f.y, (f16)f.z, (f16)f.w};
    *(f16x4*)&Wall[(size_t)i4 * 4] = h;
    if (i4 < 4096) {
        int c2 = i4 >> 10;
        const float* bb = c2 == 0 ? bq : c2 == 1 ? bk : c2 == 2 ? bv : bc;
        ball[i4] = bb[i4 & 1023];
    }
    if (i4 < 66560) {   // (64*64*64 + 64*64)/4 floats of kv+ks
        *(float4*)&kvz[i4 * 4] = (float4){0.f, 0.f, 0.f, 0.f};
    }
}

// ===========================================================================
// 256x256-tile 4-phase GEMM main loop. 512 thr = 8 waves (2M x 4N),
// per-wave 128x64 out, BK=64, dbuf LDS 128KB.
// Read-once fragments (24 ds_read_b128 / wave / K-tile, held across phases):
//   P1: stage next-A (4 issues); read afT(8)+bfL(4); barrier; Q1(16 MFMA); barrier
//   P2: stage next-B (4);        read bfH(4);        barrier; Q2;           barrier
//   P3:                          read afB(8);        barrier; Q3;           barrier
//   P4:                                                       Q4; vmcnt(0)+barrier (flip)
// Flip vmcnt(0) acts on loads issued 2-3 phases earlier (~600+cyc slack) and
// the fence-pinned barrier makes certification cross-wave (per-wave vmcnt only
// covers that wave's own staged slices).
// ===========================================================================
#define GEMM256_MAINLOOP(AB, BB)                                               \
    f32x4 acc[8][4];                                                           \
    _Pragma("unroll") for (int i = 0; i < 8; ++i)                              \
        _Pragma("unroll") for (int j = 0; j < 4; ++j)                          \
            acc[i][j] = (f32x4){0.f, 0.f, 0.f, 0.f};                           \
    f16x8 afT[4][2], afB[4][2], bfL[2][2], bfH[2][2];                          \
    stage64(As[0], AB, 0, 0, w, lane);   stage64(As[0], AB, 0, 64, w, lane);   \
    stage64(As[0], AB, 0, 128, w, lane); stage64(As[0], AB, 0, 192, w, lane);  \
    stage64(Bs[0], BB, 0, 0, w, lane);   stage64(Bs[0], BB, 0, 64, w, lane);   \
    stage64(Bs[0], BB, 0, 128, w, lane); stage64(Bs[0], BB, 0, 192, w, lane);  \
    asm volatile("s_waitcnt vmcnt(0)" ::: "memory");                           \
    __builtin_amdgcn_s_barrier();                                              \
    FENCE();                                                                   \
    for (int kt = 0; kt < 16; ++kt) {                                          \
        const int cur = kt & 1, nxt = cur ^ 1;                                 \
        const int kn = (kt + 1) * 64;                                          \
        const f16* cA = As[cur]; const f16* cB = Bs[cur];                      \
        const bool st = (kt < 15);                                             \
        /* ---------------- P1 ---------------- */                             \
        if (st) {                                                              \
            stage64(As[nxt], AB, kn, 0, w, lane);                              \
            stage64(As[nxt], AB, kn, 64, w, lane);                             \
            stage64(As[nxt], AB, kn, 128, w, lane);                            \
            stage64(As[nxt], AB, kn, 192, w, lane);                            \
        }                                                                      \
        _Pragma("unroll") for (int mi = 0; mi < 4; ++mi)                       \
            _Pragma("unroll") for (int kk = 0; kk < 2; ++kk)                   \
                afT[mi][kk] = fragld(cA, R + mi * 16 + l15, kk * 32 + l4 * 8, 64); \
        _Pragma("unroll") for (int nj = 0; nj < 2; ++nj)                       \
            _Pragma("unroll") for (int kk = 0; kk < 2; ++kk)                   \
                bfL[nj][kk] = fragld(cB, Cb + nj * 16 + l15, kk * 32 + l4 * 8, 64); \
        __builtin_amdgcn_s_barrier();                                          \
        __builtin_amdgcn_s_setprio(1);                                         \
        _Pragma("unroll") for (int kk = 0; kk < 2; ++kk)                       \
            _Pragma("unroll") for (int mi = 0; mi < 4; ++mi)                   \
                _Pragma("unroll") for (int nj = 0; nj < 2; ++nj)               \
                    acc[mi][nj] = mfma16(afT[mi][kk], bfL[nj][kk], acc[mi][nj]); \
        __builtin_amdgcn_s_setprio(0);                                         \
        __builtin_amdgcn_s_barrier();                                          \
        /* ---------------- P2 ---------------- */                             \
        if (st) {                                                              \
            stage64(Bs[nxt], BB, kn, 0, w, lane);                              \
            stage64(Bs[nxt], BB, kn, 64, w, lane);                             \
            stage64(Bs[nxt], BB, kn, 128, w, lane);                            \
            stage64(Bs[nxt], BB, kn, 192, w, lane);                            \
        }                                                                      \
        _Pragma("unroll") for (int nj = 0; nj < 2; ++nj)                       \
            _Pragma("unroll") for (int kk = 0; kk < 2; ++kk)                   \
                bfH[nj][kk] = fragld(cB, Cb + 32 + nj * 16 + l15, kk * 32 + l4 * 8, 64); \
        __builtin_amdgcn_s_barrier();                                          \
        __builtin_amdgcn_s_setprio(1);                                         \
        _Pragma("unroll") for (int kk = 0; kk < 2; ++kk)                       \
            _Pragma("unroll") for (int mi = 0; mi < 4; ++mi)                   \
                _Pragma("unroll") for (int nj = 0; nj < 2; ++nj)               \
                    acc[mi][2 + nj] = mfma16(afT[mi][kk], bfH[nj][kk], acc[mi][2 + nj]); \
        __builtin_amdgcn_s_setprio(0);                                         \
        __builtin_amdgcn_s_barrier();                                          \
        /* ---------------- P3 ---------------- */                             \
        _Pragma("unroll") for (int mi = 0; mi < 4; ++mi)                       \
            _Pragma("unroll") for (int kk = 0; kk < 2; ++kk)                   \
                afB[mi][kk] = fragld(cA, R + 64 + mi * 16 + l15, kk * 32 + l4 * 8, 64); \
        __builtin_amdgcn_s_barrier();                                          \
        __builtin_amdgcn_s_setprio(1);                                         \
        _Pragma("unroll") for (int kk = 0; kk < 2; ++kk)                       \
            _Pragma("unroll") for (int mi = 0; mi < 4; ++mi)                   \
                _Pragma("unroll") for (int nj = 0; nj < 2; ++nj)               \
                    acc[4 + mi][nj] = mfma16(afB[mi][kk], bfL[nj][kk], acc[4 + mi][nj]); \
        __builtin_amdgcn_s_setprio(0);                                         \
        __builtin_amdgcn_s_barrier();                                          \
        /* ---------------- P4 ---------------- */                             \
        __builtin_amdgcn_s_setprio(1);                                         \
        _Pragma("unroll") for (int kk = 0; kk < 2; ++kk)                       \
            _Pragma("unroll") for (int mi = 0; mi < 4; ++mi)                   \
                _Pragma("unroll") for (int nj = 0; nj < 2; ++nj)               \
                    acc[4 + mi][2 + nj] = mfma16(afB[mi][kk], bfH[nj][kk], acc[4 + mi][2 + nj]); \
        __builtin_amdgcn_s_setprio(0);                                         \
        asm volatile("s_waitcnt vmcnt(0)" ::: "memory");                       \
        __builtin_amdgcn_s_barrier();                                          \
        FENCE();                                                               \
    }

// ---------------------------------------------------------------------------
// gemm_qkv256: C[16384,3072] = xh @ Wall[0:3072]^T; class epilogues.
// Raster: each XCD owns 8 m-tiles x all 12 n-tiles (A set 4MB ~= L2).
// ---------------------------------------------------------------------------
__global__ __launch_bounds__(512) void gemm_qkv256(
    const f16* __restrict__ xh, const f16* __restrict__ Wall,
    const float* __restrict__ ball,
    f16* __restrict__ q, f16* __restrict__ kT, f16* __restrict__ vT)
{
    __shared__ __align__(16) f16 As[2][256 * 64];
    __shared__ __align__(16) f16 Bs[2][256 * 64];

    const int tid = threadIdx.x, lane = tid & 63, w = tid >> 6;
    const int wr = w >> 2, wc = w & 3;
    const int l15 = lane & 15, l4 = lane >> 4;
    const int R = wr * 128, Cb = wc * 64;

    // bijective: 768 = 8 xcd * 12 n * 8 mloc
    const int orig = blockIdx.x;
    const int xcd = orig & 7;
    const int local = orig >> 3;          // 0..95
    const int ntile = local >> 3;         // 0..11
    const int mloc = local & 7;
    const int m0 = (xcd * 8 + mloc) * 256;
    const int n0 = ntile * 256;
    const int cls = n0 >> 10;

    const f16* Ab = xh + (size_t)m0 * EMBED;
    const f16* Bb = Wall + (size_t)n0 * EMBED;

    GEMM256_MAINLOOP(Ab, Bb)

    if (cls == 0) {
        #pragma unroll
        for (int nj = 0; nj < 4; ++nj) {
            int c = n0 + Cb + nj * 16 + l15;
            float bj = ball[c];
            #pragma unroll
            for (int mi = 0; mi < 8; ++mi) {
                #pragma unroll
                for (int r = 0; r < 4; ++r) {
                    int t = m0 + R + mi * 16 + l4 * 4 + r;
                    q[(size_t)t * EMBED + c] = (f16)elu1(acc[mi][nj][r] + bj);
                }
            }
        }
    } else {
        f16* dst = (cls == 1) ? kT : vT;
        const bool act = (cls == 1);
        #pragma unroll
        for (int nj = 0; nj < 4; ++nj) {
            int n = n0 + Cb + nj * 16 + l15;
            int d = n & 1023;
            float bj = ball[n];
            #pragma unroll
            for (int mi = 0; mi < 8; ++mi) {
                int t = m0 + R + mi * 16 + l4 * 4;
                f16x4 hv;
                #pragma unroll
                for (int r = 0; r < 4; ++r) {
                    float v = acc[mi][nj][r] + bj;
                    if (act) v = elu1(v);
                    hv[r] = (f16)v;
                }
                *(f16x4*)&dst[(size_t)d * MROWS + t] = hv;
            }
        }
    }
}

// ---------------------------------------------------------------------------
// gemm_out256: out[16384,1024] = y @ Wc^T + bc (Wc = Wall rows 3072+), fp32.
// ---------------------------------------------------------------------------
__global__ __launch_bounds__(512) void gemm_out256(
    const f16* __restrict__ y, const f16* __restrict__ Wall,
    const float* __restrict__ ball, float* __restrict__ out)
{
    __shared__ __align__(16) f16 As[2][256 * 64];
    __shared__ __align__(16) f16 Bs[2][256 * 64];

    const int tid = threadIdx.x, lane = tid & 63, w = tid >> 6;
    const int wr = w >> 2, wc = w & 3;
    const int l15 = lane & 15, l4 = lane >> 4;
    const int R = wr * 128, Cb = wc * 64;

    // bijective: 256 = 8 xcd * 4 n * 8 mloc
    const int orig = blockIdx.x;
    const int xcd = orig & 7;
    const int local = orig >> 3;          // 0..31
    const int ntile = local >> 3;         // 0..3
    const int mloc = local & 7;
    const int m0 = (xcd * 8 + mloc) * 256;
    const int n0 = ntile * 256;

    const f16* Ab = y + (size_t)m0 * EMBED;
    const f16* Bb = Wall + (size_t)(3072 + n0) * EMBED;

    GEMM256_MAINLOOP(Ab, Bb)

    #pragma unroll
    for (int nj = 0; nj < 4; ++nj) {
        int n = n0 + Cb + nj * 16 + l15;
        float bj = ball[3072 + n];
        #pragma unroll
        for (int mi = 0; mi < 8; ++mi) {
            #pragma unroll
            for (int r = 0; r < 4; ++r) {
                int m = m0 + R + mi * 16 + l4 * 4 + r;
                out[(size_t)m * EMBED + n] = acc[mi][nj][r] + bj;
            }
        }
    }
}

// ---------------------------------------------------------------------------
// kv_ksum: per (bh, 512-t chunk): kvg[e][d] += sum_t v[t,e] k[t,d] (MFMA),
// ksg[d] += sum_t k[t,d]. Inputs kT,vT are [1024 d][16384 t] f16.
// ---------------------------------------------------------------------------
__global__ __launch_bounds__(256) void kv_ksum(
    const f16* __restrict__ kT, const f16* __restrict__ vT,
    float* __restrict__ kvg, float* __restrict__ ksg)
{
    __shared__ __align__(16) f16 kl[64 * 128];
    __shared__ __align__(16) f16 vl[64 * 128];

    const int bh = blockIdx.x, b = bh >> 4, h = bh & 15;
    const int tid = threadIdx.x, lane = tid & 63, w = tid >> 6;
    const int l15 = lane & 15, l4 = lane >> 4;
    const int tbase = b * TSEQ + blockIdx.y * 512;

    f32x4 kvacc[4];
    #pragma unroll
    for (int j = 0; j < 4; ++j) kvacc[j] = (f32x4){0.f, 0.f, 0.f, 0.f};
    float ksacc = 0.f;

    for (int ss = 0; ss < 4; ++ss) {
        const int tg = tbase + ss * 128;
        #pragma unroll
        for (int c = 0; c < 4; ++c) {
            int idx = tid + c * 256;
            int row = idx >> 4, t8 = (idx & 15) << 3;
            f16x8 a = *(const f16x8*)&kT[(size_t)(h * 64 + row) * MROWS + tg + t8];
            *(f16x8*)&kl[swzc(row, t8, 128)] = a;
            f16x8 bb = *(const f16x8*)&vT[(size_t)(h * 64 + row) * MROWS + tg + t8];
            *(f16x8*)&vl[swzc(row, t8, 128)] = bb;
        }
        __syncthreads();
        #pragma unroll
        for (int kk = 0; kk < 128; kk += 32) {
            f16x8 a = fragld(vl, 16 * w + l15, kk + l4 * 8, 128);
            #pragma unroll
            for (int j = 0; j < 4; ++j) {
                f16x8 bfr = fragld(kl, j * 16 + l15, kk + l4 * 8, 128);
                kvacc[j] = mfma16(a, bfr, kvacc[j]);
            }
        }
        {
            int d = tid & 63, qq = tid >> 6;
            #pragma unroll
            for (int t8 = 0; t8 < 32; t8 += 8) {
                f16x8 kv8 = fragld(kl, d, qq * 32 + t8, 128);
                #pragma unroll
                for (int e = 0; e < 8; ++e) ksacc += (float)kv8[e];
            }
        }
        __syncthreads();
    }

    #pragma unroll
    for (int j = 0; j < 4; ++j)
        #pragma unroll
        for (int r = 0; r < 4; ++r)
            atomicAdd(&kvg[(size_t)bh * 4096 +
                           (size_t)(16 * w + l4 * 4 + r) * HD + j * 16 + l15],
                      kvacc[j][r]);
    atomicAdd(&ksg[bh * HD + (tid & 63)], ksacc);
}

// ---------------------------------------------------------------------------
// y_kernel: per (bh, 128 t): z[t]=1/(q.ks+1e-6); y[t][e]=sum_d q[t,d]kv[d,e]*z
// ---------------------------------------------------------------------------
__global__ __launch_bounds__(256) void y_kernel(
    const f16* __restrict__ q, const float* __restrict__ kvg,
    const float* __restrict__ ksg, f16* __restrict__ y)
{
    __shared__ __align__(16) f16 qs[128 * 64];
    __shared__ __align__(16) f16 kvs[64 * 64];
    __shared__ __align__(16) f16 ylds[128 * 64];
    __shared__ float kss[64];
    __shared__ float zs[128];

    const int bh = blockIdx.x, b = bh >> 4, h = bh & 15;
    const int tid = threadIdx.x, lane = tid & 63, w = tid >> 6;
    const int l15 = lane & 15, l4 = lane >> 4;
    const int t0g = b * TSEQ + blockIdx.y * 128;

    #pragma unroll
    for (int c = 0; c < 4; ++c) {
        int idx = tid + c * 256;
        int row = idx >> 3, col8 = (idx & 7) << 3;
        f16x8 v = *(const f16x8*)&q[(size_t)(t0g + row) * EMBED + h * 64 + col8];
        *(f16x8*)&qs[swzc(row, col8, 64)] = v;
    }
    #pragma unroll
    for (int c = 0; c < 4; ++c) {
        int idx = tid + c * 256;
        int e = idx >> 4, d4 = (idx & 15) << 2;
        float4 f = *(const float4*)&kvg[(size_t)bh * 4096 + e * 64 + d4];
        f16x4 hv = {(f16)f.x, (f16)f.y, (f16)f.z, (f16)f.w};
        *(f16x4*)&kvs[swzc(e, d4, 64)] = hv;
    }
    if (tid < 64) kss[tid] = ksg[bh * HD + tid];
    __syncthreads();

    {
        int t = tid >> 1, dh = (tid & 1) * 32;
        float s = 0.f;
        #pragma unroll
        for (int d8 = 0; d8 < 32; d8 += 8) {
            f16x8 qv = fragld(qs, t, dh + d8, 64);
            #pragma unroll
            for (int e = 0; e < 8; ++e) s += (float)qv[e] * kss[dh + d8 + e];
        }
        s += __shfl_xor(s, 1);
        if ((tid & 1) == 0) zs[t] = 1.f / (s + 1e-6f);
    }
    __syncthreads();

    f32x4 yacc[8];
    #pragma unroll
    for (int jn = 0; jn < 8; ++jn) yacc[jn] = (f32x4){0.f, 0.f, 0.f, 0.f};
    #pragma unroll
    for (int kk = 0; kk < 64; kk += 32) {
        f16x8 a = fragld(kvs, 16 * w + l15, kk + l4 * 8, 64);
        #pragma unroll
        for (int jn = 0; jn < 8; ++jn) {
            f16x8 bq8 = fragld(qs, jn * 16 + l15, kk + l4 * 8, 64);
            yacc[jn] = mfma16(a, bq8, yacc[jn]);
        }
    }
    #pragma unroll
    for (int jn = 0; jn < 8; ++jn) {
        int t = jn * 16 + l15;
        float z = zs[t];
        int e0 = 16 * w + l4 * 4;
        f16x4 hv;
        #pragma unroll
        for (int r = 0; r < 4; ++r) hv[r] = (f16)(yacc[jn][r] * z);
        *(f16x4*)&ylds[swzc(t, e0, 64)] = hv;
    }
    __syncthreads();

    {
        int row = tid >> 1, eh = (tid & 1) * 32;
        size_t gb = (size_t)(t0g + row) * EMBED + h * 64 + eh;
        #pragma unroll
        for (int c8 = 0; c8 < 32; c8 += 8) {
            f16x8 v = fragld(ylds, row, eh + c8, 64);
            *(f16x8*)&y[gb + c8] = v;
        }
    }
}

// ---------------------------------------------------------------------------
extern "C" void kernel_launch(void* const* d_in, const int* in_sizes, int n_in,
                              void* d_out, int out_size, void* d_ws, size_t ws_size,
                              hipStream_t stream) {
    (void)in_sizes; (void)n_in; (void)out_size; (void)ws_size;
    const float* x  = (const float*)d_in[0];
    const float* Wq = (const float*)d_in[1];
    const float* bq = (const float*)d_in[2];
    const float* Wk = (const float*)d_in[3];
    const float* bk = (const float*)d_in[4];
    const float* Wv = (const float*)d_in[5];
    const float* bv = (const float*)d_in[6];
    const float* Wc = (const float*)d_in[7];
    const float* bc = (const float*)d_in[8];
    float* out = (float*)d_out;

    char* W = (char*)d_ws;
    f16* xh   = (f16*)W;
    f16* q_ws = (f16*)(W + 33554432);
    f16* kT   = (f16*)(W + 67108864);
    f16* vT   = (f16*)(W + 100663296);
    f16* Wall = (f16*)(W + 134217728);
    float* ball = (float*)(W + 142606336);
    float* kvg  = (float*)(W + 142622720);
    float* ksg  = (float*)(W + 143671296);

    cvt_x<<<16384, 256, 0, stream>>>(x, xh);
    pack_w<<<4096, 256, 0, stream>>>(Wq, Wk, Wv, Wc, bq, bk, bv, bc, Wall, ball, kvg);

    gemm_qkv256<<<768, 512, 0, stream>>>(xh, Wall, ball, q_ws, kT, vT);

    kv_ksum<<<dim3(BH, 8), 256, 0, stream>>>(kT, vT, kvg, ksg);

    y_kernel<<<dim3(BH, TSEQ / 128), 256, 0, stream>>>(q_ws, kvg, ksg, q_ws);

    gemm_out256<<<256, 512, 0, stream>>>(q_ws, Wall, ball, out);
}

// Round 9
// 241.090 us; speedup vs baseline: 1.1930x; 1.0635x over previous
//
#include <hip/hip_runtime.h>
#include <math.h>

#define EMBED 1024
#define HEADS 16
#define HD 64
#define BATCH 4
#define TSEQ 4096
#define BH (BATCH * HEADS)
#define MROWS (BATCH * TSEQ)   // 16384

typedef _Float16 f16;
typedef __attribute__((ext_vector_type(4))) _Float16 f16x4;
typedef __attribute__((ext_vector_type(8))) _Float16 f16x8;
typedef __attribute__((ext_vector_type(4))) float f32x4;

#define GLOBAL_AS __attribute__((address_space(1)))
#define LDS_AS __attribute__((address_space(3)))

__device__ __forceinline__ float elu1(float v) {
    return v > 0.f ? v + 1.f : __expf(v);
}

// XOR-swizzled element offset in a [rows][cols] f16 tile; 16B granules.
__device__ __forceinline__ int swzc(int row, int col, int cols) {
    int g = (col >> 3) ^ (row & 7);
    return row * cols + (g << 3) + (col & 7);
}

__device__ __forceinline__ f16x8 fragld(const f16* t, int row, int k, int cols) {
    return *(const f16x8*)&t[swzc(row, k, cols)];
}

__device__ __forceinline__ f32x4 mfma16(f16x8 a, f16x8 b, f32x4 c) {
    return __builtin_amdgcn_mfma_f32_16x16x32_f16(a, b, c, 0, 0, 0);
}

// async global->LDS, 16B per lane. lds dest must be wave-uniform base.
__device__ __forceinline__ void gld_lds16(const f16* g, f16* l) {
    __builtin_amdgcn_global_load_lds((const GLOBAL_AS void*)g, (LDS_AS void*)l, 16, 0, 0);
}

// ---------------------------------------------------------------------------
// prep: blocks [0,16384): x fp32 -> f16.  blocks [16384,20480): pack weights
// f16 + biases + zero kv/ks accumulators.
// ---------------------------------------------------------------------------
__global__ __launch_bounds__(256) void prep(
    const float* __restrict__ x, f16* __restrict__ xh,
    const float* __restrict__ Wq, const float* __restrict__ Wk,
    const float* __restrict__ Wv, const float* __restrict__ Wc,
    const float* __restrict__ bq, const float* __restrict__ bk,
    const float* __restrict__ bv, const float* __restrict__ bc,
    f16* __restrict__ Wall, float* __restrict__ ball, float* __restrict__ kvz)
{
    int bid = blockIdx.x;
    if (bid < 16384) {
        size_t i4 = (size_t)bid * 256 + threadIdx.x;
        float4 f = *(const float4*)&x[i4 * 4];
        f16x4 h = {(f16)f.x, (f16)f.y, (f16)f.z, (f16)f.w};
        *(f16x4*)&xh[i4 * 4] = h;
    } else {
        int i4 = (bid - 16384) * 256 + threadIdx.x;    // < 1048576
        int cls = i4 >> 18;
        const float* W = cls == 0 ? Wq : cls == 1 ? Wk : cls == 2 ? Wv : Wc;
        int off = (i4 & 0x3FFFF) * 4;
        float4 f = *(const float4*)&W[off];
        f16x4 h = {(f16)f.x, (f16)f.y, (f16)f.z, (f16)f.w};
        *(f16x4*)&Wall[(size_t)i4 * 4] = h;
        if (i4 < 4096) {
            int c2 = i4 >> 10;
            const float* bb = c2 == 0 ? bq : c2 == 1 ? bk : c2 == 2 ? bv : bc;
            ball[i4] = bb[i4 & 1023];
        }
        if (i4 < 66560) {   // (64*64*64 + 64*64)/4 floats of kv+ks
            *(float4*)&kvz[i4 * 4] = (float4){0.f, 0.f, 0.f, 0.f};
        }
    }
}

// ---------------------------------------------------------------------------
// gemm_qkv: C[16384, 3072] = xh @ Wall[0:3072]^T, f16 MFMA, fp32 acc.
// 128x128 tile, BK=64, 256 thr, 2-phase (proven r5 structure).
// XCD raster: 3072 wgs = 8 xcd x 16 mloc x 24 ntile; A-set/XCD = 4MB ~ L2.
// ---------------------------------------------------------------------------
__global__ __launch_bounds__(256) void gemm_qkv(
    const f16* __restrict__ xh, const f16* __restrict__ Wall,
    const float* __restrict__ ball,
    f16* __restrict__ q, f16* __restrict__ kT, f16* __restrict__ vT)
{
    __shared__ __align__(16) f16 As[128 * 64];
    __shared__ __align__(16) f16 Bs[128 * 64];

    const int tid = threadIdx.x, lane = tid & 63, w = tid >> 6;
    const int wr = w >> 1, wc4 = w & 1, l15 = lane & 15, l4 = lane >> 4;

    const int orig = blockIdx.x;          // 0..3071
    const int xcd = orig & 7;
    const int local = orig >> 3;          // 0..383
    const int ntile = local >> 4;         // 0..23
    const int mloc = local & 15;
    const int m0 = (xcd * 16 + mloc) * 128;
    const int n0 = ntile * 128;
    const int cls = n0 >> 10;

    // inverse-swizzled source column (elems) + row-within-chunk, lane-only
    const int gcol = ((lane & 7) ^ (lane >> 3)) << 3;
    const int rsub = lane >> 3;
    const size_t arow = (size_t)(m0 + w * 32 + rsub) * EMBED + gcol;
    const size_t brow = (size_t)(n0 + w * 32 + rsub) * EMBED + gcol;

    f32x4 acc[4][4];
    #pragma unroll
    for (int i = 0; i < 4; ++i)
        #pragma unroll
        for (int j = 0; j < 4; ++j) acc[i][j] = (f32x4){0.f, 0.f, 0.f, 0.f};

    for (int k0 = 0; k0 < EMBED; k0 += 64) {
        #pragma unroll
        for (int c = 0; c < 4; ++c) {
            gld_lds16(&xh[arow + (size_t)c * 8 * EMBED + k0], &As[(w * 4 + c) * 512]);
            gld_lds16(&Wall[brow + (size_t)c * 8 * EMBED + k0], &Bs[(w * 4 + c) * 512]);
        }
        __syncthreads();
        #pragma unroll
        for (int kk = 0; kk < 64; kk += 32) {
            f16x8 af[4], bf[4];
            #pragma unroll
            for (int i = 0; i < 4; ++i)
                af[i] = fragld(As, wr * 64 + i * 16 + l15, kk + l4 * 8, 64);
            #pragma unroll
            for (int j = 0; j < 4; ++j)
                bf[j] = fragld(Bs, wc4 * 64 + j * 16 + l15, kk + l4 * 8, 64);
            #pragma unroll
            for (int i = 0; i < 4; ++i)
                #pragma unroll
                for (int j = 0; j < 4; ++j)
                    acc[i][j] = mfma16(af[i], bf[j], acc[i][j]);
        }
        __syncthreads();
    }

    if (cls == 0) {
        #pragma unroll
        for (int j = 0; j < 4; ++j) {
            int c = n0 + wc4 * 64 + j * 16 + l15;
            float bj = ball[c];
            #pragma unroll
            for (int i = 0; i < 4; ++i) {
                #pragma unroll
                for (int r = 0; r < 4; ++r) {
                    int t = m0 + wr * 64 + i * 16 + l4 * 4 + r;
                    q[(size_t)t * EMBED + c] = (f16)elu1(acc[i][j][r] + bj);
                }
            }
        }
    } else {
        f16* dst = (cls == 1) ? kT : vT;
        const bool act = (cls == 1);
        #pragma unroll
        for (int j = 0; j < 4; ++j) {
            int n = n0 + wc4 * 64 + j * 16 + l15;
            int d = n & 1023;
            float bj = ball[n];
            #pragma unroll
            for (int i = 0; i < 4; ++i) {
                int t = m0 + wr * 64 + i * 16 + l4 * 4;
                f16x4 hv;
                #pragma unroll
                for (int r = 0; r < 4; ++r) {
                    float v = acc[i][j][r] + bj;
                    if (act) v = elu1(v);
                    hv[r] = (f16)v;
                }
                *(f16x4*)&dst[(size_t)d * MROWS + t] = hv;
            }
        }
    }
}

// ---------------------------------------------------------------------------
// kv_ksum: per (bh, 512-t chunk): kvg[e][d] += sum_t v[t,e] k[t,d] (MFMA),
// ksg[d] += sum_t k[t,d]. Inputs kT,vT are [1024 d][16384 t] f16.
// ---------------------------------------------------------------------------
__global__ __launch_bounds__(256) void kv_ksum(
    const f16* __restrict__ kT, const f16* __restrict__ vT,
    float* __restrict__ kvg, float* __restrict__ ksg)
{
    __shared__ __align__(16) f16 kl[64 * 128];
    __shared__ __align__(16) f16 vl[64 * 128];

    const int bh = blockIdx.x, b = bh >> 4, h = bh & 15;
    const int tid = threadIdx.x, lane = tid & 63, w = tid >> 6;
    const int l15 = lane & 15, l4 = lane >> 4;
    const int tbase = b * TSEQ + blockIdx.y * 512;

    f32x4 kvacc[4];
    #pragma unroll
    for (int j = 0; j < 4; ++j) kvacc[j] = (f32x4){0.f, 0.f, 0.f, 0.f};
    float ksacc = 0.f;

    for (int ss = 0; ss < 4; ++ss) {
        const int tg = tbase + ss * 128;
        #pragma unroll
        for (int c = 0; c < 4; ++c) {
            int idx = tid + c * 256;
            int row = idx >> 4, t8 = (idx & 15) << 3;
            f16x8 a = *(const f16x8*)&kT[(size_t)(h * 64 + row) * MROWS + tg + t8];
            *(f16x8*)&kl[swzc(row, t8, 128)] = a;
            f16x8 bb = *(const f16x8*)&vT[(size_t)(h * 64 + row) * MROWS + tg + t8];
            *(f16x8*)&vl[swzc(row, t8, 128)] = bb;
        }
        __syncthreads();
        #pragma unroll
        for (int kk = 0; kk < 128; kk += 32) {
            f16x8 a = fragld(vl, 16 * w + l15, kk + l4 * 8, 128);
            #pragma unroll
            for (int j = 0; j < 4; ++j) {
                f16x8 bfr = fragld(kl, j * 16 + l15, kk + l4 * 8, 128);
                kvacc[j] = mfma16(a, bfr, kvacc[j]);
            }
        }
        {
            int d = tid & 63, qq = tid >> 6;
            #pragma unroll
            for (int t8 = 0; t8 < 32; t8 += 8) {
                f16x8 kv8 = fragld(kl, d, qq * 32 + t8, 128);
                #pragma unroll
                for (int e = 0; e < 8; ++e) ksacc += (float)kv8[e];
            }
        }
        __syncthreads();
    }

    #pragma unroll
    for (int j = 0; j < 4; ++j)
        #pragma unroll
        for (int r = 0; r < 4; ++r)
            atomicAdd(&kvg[(size_t)bh * 4096 +
                           (size_t)(16 * w + l4 * 4 + r) * HD + j * 16 + l15],
                      kvacc[j][r]);
    atomicAdd(&ksg[bh * HD + (tid & 63)], ksacc);
}

// ---------------------------------------------------------------------------
// y_kernel: per (bh, 128 t): z[t]=1/(q.ks+1e-6); y[t][e]=sum_d q[t,d]kv[d,e]*z
// ---------------------------------------------------------------------------
__global__ __launch_bounds__(256) void y_kernel(
    const f16* __restrict__ q, const float* __restrict__ kvg,
    const float* __restrict__ ksg, f16* __restrict__ y)
{
    __shared__ __align__(16) f16 qs[128 * 64];
    __shared__ __align__(16) f16 kvs[64 * 64];
    __shared__ __align__(16) f16 ylds[128 * 64];
    __shared__ float kss[64];
    __shared__ float zs[128];

    const int bh = blockIdx.x, b = bh >> 4, h = bh & 15;
    const int tid = threadIdx.x, lane = tid & 63, w = tid >> 6;
    const int l15 = lane & 15, l4 = lane >> 4;
    const int t0g = b * TSEQ + blockIdx.y * 128;

    #pragma unroll
    for (int c = 0; c < 4; ++c) {
        int idx = tid + c * 256;
        int row = idx >> 3, col8 = (idx & 7) << 3;
        f16x8 v = *(const f16x8*)&q[(size_t)(t0g + row) * EMBED + h * 64 + col8];
        *(f16x8*)&qs[swzc(row, col8, 64)] = v;
    }
    #pragma unroll
    for (int c = 0; c < 4; ++c) {
        int idx = tid + c * 256;
        int e = idx >> 4, d4 = (idx & 15) << 2;
        float4 f = *(const float4*)&kvg[(size_t)bh * 4096 + e * 64 + d4];
        f16x4 hv = {(f16)f.x, (f16)f.y, (f16)f.z, (f16)f.w};
        *(f16x4*)&kvs[swzc(e, d4, 64)] = hv;
    }
    if (tid < 64) kss[tid] = ksg[bh * HD + tid];
    __syncthreads();

    {
        int t = tid >> 1, dh = (tid & 1) * 32;
        float s = 0.f;
        #pragma unroll
        for (int d8 = 0; d8 < 32; d8 += 8) {
            f16x8 qv = fragld(qs, t, dh + d8, 64);
            #pragma unroll
            for (int e = 0; e < 8; ++e) s += (float)qv[e] * kss[dh + d8 + e];
        }
        s += __shfl_xor(s, 1);
        if ((tid & 1) == 0) zs[t] = 1.f / (s + 1e-6f);
    }
    __syncthreads();

    f32x4 yacc[8];
    #pragma unroll
    for (int jn = 0; jn < 8; ++jn) yacc[jn] = (f32x4){0.f, 0.f, 0.f, 0.f};
    #pragma unroll
    for (int kk = 0; kk < 64; kk += 32) {
        f16x8 a = fragld(kvs, 16 * w + l15, kk + l4 * 8, 64);
        #pragma unroll
        for (int jn = 0; jn < 8; ++jn) {
            f16x8 bq8 = fragld(qs, jn * 16 + l15, kk + l4 * 8, 64);
            yacc[jn] = mfma16(a, bq8, yacc[jn]);
        }
    }
    #pragma unroll
    for (int jn = 0; jn < 8; ++jn) {
        int t = jn * 16 + l15;
        float z = zs[t];
        int e0 = 16 * w + l4 * 4;
        f16x4 hv;
        #pragma unroll
        for (int r = 0; r < 4; ++r) hv[r] = (f16)(yacc[jn][r] * z);
        *(f16x4*)&ylds[swzc(t, e0, 64)] = hv;
    }
    __syncthreads();

    {
        int row = tid >> 1, eh = (tid & 1) * 32;
        size_t gb = (size_t)(t0g + row) * EMBED + h * 64 + eh;
        #pragma unroll
        for (int c8 = 0; c8 < 32; c8 += 8) {
            f16x8 v = fragld(ylds, row, eh + c8, 64);
            *(f16x8*)&y[gb + c8] = v;
        }
    }
}

// ---------------------------------------------------------------------------
// gemm_out: out[M,1024] = y @ Wc^T + bc (Wc = Wall rows 3072..4095), fp32 out.
// XCD raster: 1024 wgs = 8 xcd x 16 mloc x 8 ntile.
// ---------------------------------------------------------------------------
__global__ __launch_bounds__(256) void gemm_out(
    const f16* __restrict__ y, const f16* __restrict__ Wall,
    const float* __restrict__ ball, float* __restrict__ out)
{
    __shared__ __align__(16) f16 As[128 * 64];
    __shared__ __align__(16) f16 Bs[128 * 64];

    const int tid = threadIdx.x, lane = tid & 63, w = tid >> 6;
    const int wr = w >> 1, wc4 = w & 1, l15 = lane & 15, l4 = lane >> 4;

    const int orig = blockIdx.x;          // 0..1023
    const int xcd = orig & 7;
    const int local = orig >> 3;          // 0..127
    const int ntile = local >> 4;         // 0..7
    const int mloc = local & 15;
    const int m0 = (xcd * 16 + mloc) * 128;
    const int n0 = ntile * 128;

    const int gcol = ((lane & 7) ^ (lane >> 3)) << 3;
    const int rsub = lane >> 3;
    const size_t arow = (size_t)(m0 + w * 32 + rsub) * EMBED + gcol;
    const size_t brow = (size_t)(3072 + n0 + w * 32 + rsub) * EMBED + gcol;

    f32x4 acc[4][4];
    #pragma unroll
    for (int i = 0; i < 4; ++i)
        #pragma unroll
        for (int j = 0; j < 4; ++j) acc[i][j] = (f32x4){0.f, 0.f, 0.f, 0.f};

    for (int k0 = 0; k0 < EMBED; k0 += 64) {
        #pragma unroll
        for (int c = 0; c < 4; ++c) {
            gld_lds16(&y[arow + (size_t)c * 8 * EMBED + k0], &As[(w * 4 + c) * 512]);
            gld_lds16(&Wall[brow + (size_t)c * 8 * EMBED + k0], &Bs[(w * 4 + c) * 512]);
        }
        __syncthreads();
        #pragma unroll
        for (int kk = 0; kk < 64; kk += 32) {
            f16x8 af[4], bf[4];
            #pragma unroll
            for (int i = 0; i < 4; ++i)
                af[i] = fragld(As, wr * 64 + i * 16 + l15, kk + l4 * 8, 64);
            #pragma unroll
            for (int j = 0; j < 4; ++j)
                bf[j] = fragld(Bs, wc4 * 64 + j * 16 + l15, kk + l4 * 8, 64);
            #pragma unroll
            for (int i = 0; i < 4; ++i)
                #pragma unroll
                for (int j = 0; j < 4; ++j)
                    acc[i][j] = mfma16(af[i], bf[j], acc[i][j]);
        }
        __syncthreads();
    }

    #pragma unroll
    for (int j = 0; j < 4; ++j) {
        int n = n0 + wc4 * 64 + j * 16 + l15;
        float bj = ball[3072 + n];
        #pragma unroll
        for (int i = 0; i < 4; ++i) {
            #pragma unroll
            for (int r = 0; r < 4; ++r) {
                int m = m0 + wr * 64 + i * 16 + l4 * 4 + r;
                out[(size_t)m * EMBED + n] = acc[i][j][r] + bj;
            }
        }
    }
}

// ---------------------------------------------------------------------------
extern "C" void kernel_launch(void* const* d_in, const int* in_sizes, int n_in,
                              void* d_out, int out_size, void* d_ws, size_t ws_size,
                              hipStream_t stream) {
    (void)in_sizes; (void)n_in; (void)out_size; (void)ws_size;
    const float* x  = (const float*)d_in[0];
    const float* Wq = (const float*)d_in[1];
    const float* bq = (const float*)d_in[2];
    const float* Wk = (const float*)d_in[3];
    const float* bk = (const float*)d_in[4];
    const float* Wv = (const float*)d_in[5];
    const float* bv = (const float*)d_in[6];
    const float* Wc = (const float*)d_in[7];
    const float* bc = (const float*)d_in[8];
    float* out = (float*)d_out;

    char* W = (char*)d_ws;
    f16* xh   = (f16*)W;
    f16* q_ws = (f16*)(W + 33554432);
    f16* kT   = (f16*)(W + 67108864);
    f16* vT   = (f16*)(W + 100663296);
    f16* Wall = (f16*)(W + 134217728);
    float* ball = (float*)(W + 142606336);
    float* kvg  = (float*)(W + 142622720);
    float* ksg  = (float*)(W + 143671296);

    prep<<<20480, 256, 0, stream>>>(x, xh, Wq, Wk, Wv, Wc, bq, bk, bv, bc,
                                    Wall, ball, kvg);

    gemm_qkv<<<3072, 256, 0, stream>>>(xh, Wall, ball, q_ws, kT, vT);

    kv_ksum<<<dim3(BH, 8), 256, 0, stream>>>(kT, vT, kvg, ksg);

    y_kernel<<<dim3(BH, TSEQ / 128), 256, 0, stream>>>(q_ws, kvg, ksg, q_ws);

    gemm_out<<<1024, 256, 0, stream>>>(q_ws, Wall, ball, out);
}

// Round 10
// 226.162 us; speedup vs baseline: 1.2718x; 1.0660x over previous
//
#include <hip/hip_runtime.h>
#include <math.h>

#define EMBED 1024
#define HEADS 16
#define HD 64
#define BATCH 4
#define TSEQ 4096
#define BH (BATCH * HEADS)
#define MROWS (BATCH * TSEQ)   // 16384

typedef _Float16 f16;
typedef __attribute__((ext_vector_type(4))) _Float16 f16x4;
typedef __attribute__((ext_vector_type(8))) _Float16 f16x8;
typedef __attribute__((ext_vector_type(4))) float f32x4;

#define GLOBAL_AS __attribute__((address_space(1)))
#define LDS_AS __attribute__((address_space(3)))

__device__ __forceinline__ float elu1(float v) {
    return v > 0.f ? v + 1.f : __expf(v);
}

// XOR-swizzled element offset in a [rows][cols] f16 tile; 16B granules.
__device__ __forceinline__ int swzc(int row, int col, int cols) {
    int g = (col >> 3) ^ (row & 7);
    return row * cols + (g << 3) + (col & 7);
}

__device__ __forceinline__ f16x8 fragld(const f16* t, int row, int k, int cols) {
    return *(const f16x8*)&t[swzc(row, k, cols)];
}

__device__ __forceinline__ f32x4 mfma16(f16x8 a, f16x8 b, f32x4 c) {
    return __builtin_amdgcn_mfma_f32_16x16x32_f16(a, b, c, 0, 0, 0);
}

// async global->LDS, 16B per lane. lds dest must be wave-uniform base.
__device__ __forceinline__ void gld_lds16(const f16* g, f16* l) {
    __builtin_amdgcn_global_load_lds((const GLOBAL_AS void*)g, (LDS_AS void*)l, 16, 0, 0);
}

// ---------------------------------------------------------------------------
// prep: blocks [0,16384): x fp32 -> f16.  blocks [16384,20480): pack weights
// f16 + biases + zero kv/ks accumulators.
// ---------------------------------------------------------------------------
__global__ __launch_bounds__(256) void prep(
    const float* __restrict__ x, f16* __restrict__ xh,
    const float* __restrict__ Wq, const float* __restrict__ Wk,
    const float* __restrict__ Wv, const float* __restrict__ Wc,
    const float* __restrict__ bq, const float* __restrict__ bk,
    const float* __restrict__ bv, const float* __restrict__ bc,
    f16* __restrict__ Wall, float* __restrict__ ball, float* __restrict__ kvz)
{
    int bid = blockIdx.x;
    if (bid < 16384) {
        size_t i4 = (size_t)bid * 256 + threadIdx.x;
        float4 f = *(const float4*)&x[i4 * 4];
        f16x4 h = {(f16)f.x, (f16)f.y, (f16)f.z, (f16)f.w};
        *(f16x4*)&xh[i4 * 4] = h;
    } else {
        int i4 = (bid - 16384) * 256 + threadIdx.x;    // < 1048576
        int cls = i4 >> 18;
        const float* W = cls == 0 ? Wq : cls == 1 ? Wk : cls == 2 ? Wv : Wc;
        int off = (i4 & 0x3FFFF) * 4;
        float4 f = *(const float4*)&W[off];
        f16x4 h = {(f16)f.x, (f16)f.y, (f16)f.z, (f16)f.w};
        *(f16x4*)&Wall[(size_t)i4 * 4] = h;
        if (i4 < 4096) {
            int c2 = i4 >> 10;
            const float* bb = c2 == 0 ? bq : c2 == 1 ? bk : c2 == 2 ? bv : bc;
            ball[i4] = bb[i4 & 1023];
        }
        if (i4 < 66560) {   // (64*64*64 + 64*64)/4 floats of kv+ks
            *(float4*)&kvz[i4 * 4] = (float4){0.f, 0.f, 0.f, 0.f};
        }
    }
}

// ---------------------------------------------------------------------------
// gemm_qkv: grid (128 m-tiles, 24 n-classes), 256 thr, r5-proven 2-phase body.
//   ny in [0,8):  C = xh @ Wq^T  -> q (elu), coalesced via LDS round-trip
//   ny in [8,24): head h=ny-8, B = [Wk_h ; Wv_h] (128 rows):
//                 k=elu(C[:,0:64]+bk), v=C[:,64:128]+bv -> LDS transposed
//                 kvg[e][d] += v^T k (MFMA over 128 t), ksg[d] += sum_t k
//                 (no kT/vT in HBM, no separate kv_ksum kernel)
// ---------------------------------------------------------------------------
__global__ __launch_bounds__(256) void gemm_qkv(
    const f16* __restrict__ xh, const f16* __restrict__ Wall,
    const float* __restrict__ ball,
    f16* __restrict__ q, float* __restrict__ kvg, float* __restrict__ ksg)
{
    __shared__ __align__(16) f16 smem[2 * 128 * 64];   // As | Bs (32KB)
    f16* As = smem;
    f16* Bs = smem + 128 * 64;

    const int tid = threadIdx.x, lane = tid & 63, w = tid >> 6;
    const int wr = w >> 1, wc4 = w & 1, l15 = lane & 15, l4 = lane >> 4;

    const int m0 = blockIdx.x * 128;
    const int ny = blockIdx.y;
    const bool isq = (ny < 8);
    const int h = ny - 8;

    // inverse-swizzled source column (elems) + row-within-chunk, lane-only
    const int gcol = ((lane & 7) ^ (lane >> 3)) << 3;
    const int rsub = lane >> 3;
    const size_t arow = (size_t)(m0 + w * 32 + rsub) * EMBED + gcol;

    // B base: q -> Wall rows [ny*128, +128); kv -> split [Wk_h ; Wv_h]
    const int wrow = w * 32 + rsub;       // 0..127 (tile row this lane stages)
    int brow_idx;
    if (isq)          brow_idx = ny * 128 + wrow;
    else if (wrow < 64) brow_idx = 1024 + h * 64 + wrow;
    else                brow_idx = 2048 + h * 64 + (wrow - 64);
    const size_t brow = (size_t)brow_idx * EMBED + gcol;

    f32x4 acc[4][4];
    #pragma unroll
    for (int i = 0; i < 4; ++i)
        #pragma unroll
        for (int j = 0; j < 4; ++j) acc[i][j] = (f32x4){0.f, 0.f, 0.f, 0.f};

    for (int k0 = 0; k0 < EMBED; k0 += 64) {
        #pragma unroll
        for (int c = 0; c < 4; ++c) {
            gld_lds16(&xh[arow + (size_t)c * 8 * EMBED + k0], &As[(w * 4 + c) * 512]);
            gld_lds16(&Wall[brow + (size_t)c * 8 * EMBED + k0], &Bs[(w * 4 + c) * 512]);
        }
        __syncthreads();
        #pragma unroll
        for (int kk = 0; kk < 64; kk += 32) {
            f16x8 af[4], bf[4];
            #pragma unroll
            for (int i = 0; i < 4; ++i)
                af[i] = fragld(As, wr * 64 + i * 16 + l15, kk + l4 * 8, 64);
            #pragma unroll
            for (int j = 0; j < 4; ++j)
                bf[j] = fragld(Bs, wc4 * 64 + j * 16 + l15, kk + l4 * 8, 64);
            #pragma unroll
            for (int i = 0; i < 4; ++i)
                #pragma unroll
                for (int j = 0; j < 4; ++j)
                    acc[i][j] = mfma16(af[i], bf[j], acc[i][j]);
        }
        __syncthreads();
    }

    if (isq) {
        // ---- q epilogue: acc -> smem [128 t][128 c] swizzled -> coalesced f16x8
        const int n0 = ny * 128;
        #pragma unroll
        for (int j = 0; j < 4; ++j) {
            int c = wc4 * 64 + j * 16 + l15;
            float bj = ball[n0 + c];
            #pragma unroll
            for (int i = 0; i < 4; ++i) {
                #pragma unroll
                for (int r = 0; r < 4; ++r) {
                    int t = wr * 64 + i * 16 + l4 * 4 + r;
                    smem[swzc(t, c, 128)] = (f16)elu1(acc[i][j][r] + bj);
                }
            }
        }
        __syncthreads();
        #pragma unroll
        for (int p = 0; p < 8; ++p) {
            int idx = tid + p * 256;
            int row = idx >> 4, g8 = (idx & 15) << 3;
            f16x8 v = *(const f16x8*)&smem[swzc(row, g8, 128)];
            *(f16x8*)&q[(size_t)(m0 + row) * EMBED + n0 + g8] = v;
        }
    } else {
        // ---- kv epilogue: acc -> kt/vt LDS [64 d][128 t] (transposed, swz)
        f16* kt = As;
        f16* vt = Bs;
        const float* biasp = ball + (wc4 ? 2048 : 1024) + h * 64;
        #pragma unroll
        for (int j = 0; j < 4; ++j) {
            int d = j * 16 + l15;
            float bj = biasp[d];
            f16* dst = wc4 ? vt : kt;
            #pragma unroll
            for (int i = 0; i < 4; ++i) {
                int t0 = wr * 64 + i * 16 + l4 * 4;
                f16x4 hv;
                #pragma unroll
                for (int r = 0; r < 4; ++r) {
                    float vv = acc[i][j][r] + bj;
                    if (!wc4) vv = elu1(vv);
                    hv[r] = (f16)vv;
                }
                *(f16x4*)&dst[swzc(d, t0, 128)] = hv;
            }
        }
        __syncthreads();

        // kvg[e][d] += sum_t v[t,e] k[t,d]; wave w owns e range [16w,16w+16)
        f32x4 kvacc[4];
        #pragma unroll
        for (int j = 0; j < 4; ++j) kvacc[j] = (f32x4){0.f, 0.f, 0.f, 0.f};
        #pragma unroll
        for (int tc = 0; tc < 4; ++tc) {
            f16x8 a = fragld(vt, 16 * w + l15, tc * 32 + l4 * 8, 128);
            #pragma unroll
            for (int j = 0; j < 4; ++j) {
                f16x8 bfr = fragld(kt, j * 16 + l15, tc * 32 + l4 * 8, 128);
                kvacc[j] = mfma16(a, bfr, kvacc[j]);
            }
        }
        float ksacc = 0.f;
        {
            int d = tid & 63, q4 = tid >> 6;
            #pragma unroll
            for (int t8 = 0; t8 < 32; t8 += 8) {
                f16x8 k8 = fragld(kt, d, q4 * 32 + t8, 128);
                #pragma unroll
                for (int e = 0; e < 8; ++e) ksacc += (float)k8[e];
            }
        }
        const int bh = (m0 >> 12) * HEADS + h;
        #pragma unroll
        for (int j = 0; j < 4; ++j)
            #pragma unroll
            for (int r = 0; r < 4; ++r)
                atomicAdd(&kvg[(size_t)bh * 4096 +
                               (size_t)(16 * w + l4 * 4 + r) * HD + j * 16 + l15],
                          kvacc[j][r]);
        atomicAdd(&ksg[bh * HD + (tid & 63)], ksacc);
    }
}

// ---------------------------------------------------------------------------
// y_kernel: per (bh, 128 t): z[t]=1/(q.ks+1e-6); y[t][e]=sum_d q[t,d]kv[d,e]*z
// ---------------------------------------------------------------------------
__global__ __launch_bounds__(256) void y_kernel(
    const f16* __restrict__ q, const float* __restrict__ kvg,
    const float* __restrict__ ksg, f16* __restrict__ y)
{
    __shared__ __align__(16) f16 qs[128 * 64];
    __shared__ __align__(16) f16 kvs[64 * 64];
    __shared__ __align__(16) f16 ylds[128 * 64];
    __shared__ float kss[64];
    __shared__ float zs[128];

    const int bh = blockIdx.x, b = bh >> 4, h = bh & 15;
    const int tid = threadIdx.x, lane = tid & 63, w = tid >> 6;
    const int l15 = lane & 15, l4 = lane >> 4;
    const int t0g = b * TSEQ + blockIdx.y * 128;

    #pragma unroll
    for (int c = 0; c < 4; ++c) {
        int idx = tid + c * 256;
        int row = idx >> 3, col8 = (idx & 7) << 3;
        f16x8 v = *(const f16x8*)&q[(size_t)(t0g + row) * EMBED + h * 64 + col8];
        *(f16x8*)&qs[swzc(row, col8, 64)] = v;
    }
    #pragma unroll
    for (int c = 0; c < 4; ++c) {
        int idx = tid + c * 256;
        int e = idx >> 4, d4 = (idx & 15) << 2;
        float4 f = *(const float4*)&kvg[(size_t)bh * 4096 + e * 64 + d4];
        f16x4 hv = {(f16)f.x, (f16)f.y, (f16)f.z, (f16)f.w};
        *(f16x4*)&kvs[swzc(e, d4, 64)] = hv;
    }
    if (tid < 64) kss[tid] = ksg[bh * HD + tid];
    __syncthreads();

    {
        int t = tid >> 1, dh = (tid & 1) * 32;
        float s = 0.f;
        #pragma unroll
        for (int d8 = 0; d8 < 32; d8 += 8) {
            f16x8 qv = fragld(qs, t, dh + d8, 64);
            #pragma unroll
            for (int e = 0; e < 8; ++e) s += (float)qv[e] * kss[dh + d8 + e];
        }
        s += __shfl_xor(s, 1);
        if ((tid & 1) == 0) zs[t] = 1.f / (s + 1e-6f);
    }
    __syncthreads();

    f32x4 yacc[8];
    #pragma unroll
    for (int jn = 0; jn < 8; ++jn) yacc[jn] = (f32x4){0.f, 0.f, 0.f, 0.f};
    #pragma unroll
    for (int kk = 0; kk < 64; kk += 32) {
        f16x8 a = fragld(kvs, 16 * w + l15, kk + l4 * 8, 64);
        #pragma unroll
        for (int jn = 0; jn < 8; ++jn) {
            f16x8 bq8 = fragld(qs, jn * 16 + l15, kk + l4 * 8, 64);
            yacc[jn] = mfma16(a, bq8, yacc[jn]);
        }
    }
    #pragma unroll
    for (int jn = 0; jn < 8; ++jn) {
        int t = jn * 16 + l15;
        float z = zs[t];
        int e0 = 16 * w + l4 * 4;
        f16x4 hv;
        #pragma unroll
        for (int r = 0; r < 4; ++r) hv[r] = (f16)(yacc[jn][r] * z);
        *(f16x4*)&ylds[swzc(t, e0, 64)] = hv;
    }
    __syncthreads();

    {
        int row = tid >> 1, eh = (tid & 1) * 32;
        size_t gb = (size_t)(t0g + row) * EMBED + h * 64 + eh;
        #pragma unroll
        for (int c8 = 0; c8 < 32; c8 += 8) {
            f16x8 v = fragld(ylds, row, eh + c8, 64);
            *(f16x8*)&y[gb + c8] = v;
        }
    }
}

// ---------------------------------------------------------------------------
// gemm_out: out[M,1024] = y @ Wc^T + bc (Wc = Wall rows 3072..4095), fp32 out.
// ---------------------------------------------------------------------------
__global__ __launch_bounds__(256) void gemm_out(
    const f16* __restrict__ y, const f16* __restrict__ Wall,
    const float* __restrict__ ball, float* __restrict__ out)
{
    __shared__ __align__(16) f16 As[128 * 64];
    __shared__ __align__(16) f16 Bs[128 * 64];

    const int tid = threadIdx.x, lane = tid & 63, w = tid >> 6;
    const int wr = w >> 1, wc4 = w & 1, l15 = lane & 15, l4 = lane >> 4;
    const int m0 = blockIdx.x * 128;
    const int n0 = blockIdx.y * 128;

    const int gcol = ((lane & 7) ^ (lane >> 3)) << 3;
    const int rsub = lane >> 3;
    const size_t arow = (size_t)(m0 + w * 32 + rsub) * EMBED + gcol;
    const size_t brow = (size_t)(3072 + n0 + w * 32 + rsub) * EMBED + gcol;

    f32x4 acc[4][4];
    #pragma unroll
    for (int i = 0; i < 4; ++i)
        #pragma unroll
        for (int j = 0; j < 4; ++j) acc[i][j] = (f32x4){0.f, 0.f, 0.f, 0.f};

    for (int k0 = 0; k0 < EMBED; k0 += 64) {
        #pragma unroll
        for (int c = 0; c < 4; ++c) {
            gld_lds16(&y[arow + (size_t)c * 8 * EMBED + k0], &As[(w * 4 + c) * 512]);
            gld_lds16(&Wall[brow + (size_t)c * 8 * EMBED + k0], &Bs[(w * 4 + c) * 512]);
        }
        __syncthreads();
        #pragma unroll
        for (int kk = 0; kk < 64; kk += 32) {
            f16x8 af[4], bf[4];
            #pragma unroll
            for (int i = 0; i < 4; ++i)
                af[i] = fragld(As, wr * 64 + i * 16 + l15, kk + l4 * 8, 64);
            #pragma unroll
            for (int j = 0; j < 4; ++j)
                bf[j] = fragld(Bs, wc4 * 64 + j * 16 + l15, kk + l4 * 8, 64);
            #pragma unroll
            for (int i = 0; i < 4; ++i)
                #pragma unroll
                for (int j = 0; j < 4; ++j)
                    acc[i][j] = mfma16(af[i], bf[j], acc[i][j]);
        }
        __syncthreads();
    }

    #pragma unroll
    for (int j = 0; j < 4; ++j) {
        int n = n0 + wc4 * 64 + j * 16 + l15;
        float bj = ball[3072 + n];
        #pragma unroll
        for (int i = 0; i < 4; ++i) {
            #pragma unroll
            for (int r = 0; r < 4; ++r) {
                int m = m0 + wr * 64 + i * 16 + l4 * 4 + r;
                out[(size_t)m * EMBED + n] = acc[i][j][r] + bj;
            }
        }
    }
}

// ---------------------------------------------------------------------------
extern "C" void kernel_launch(void* const* d_in, const int* in_sizes, int n_in,
                              void* d_out, int out_size, void* d_ws, size_t ws_size,
                              hipStream_t stream) {
    (void)in_sizes; (void)n_in; (void)out_size; (void)ws_size;
    const float* x  = (const float*)d_in[0];
    const float* Wq = (const float*)d_in[1];
    const float* bq = (const float*)d_in[2];
    const float* Wk = (const float*)d_in[3];
    const float* bk = (const float*)d_in[4];
    const float* Wv = (const float*)d_in[5];
    const float* bv = (const float*)d_in[6];
    const float* Wc = (const float*)d_in[7];
    const float* bc = (const float*)d_in[8];
    float* out = (float*)d_out;

    // workspace (~77 MB): xh 32MB | q/y 32MB | Wall 8MB | ball | kvg | ksg
    char* W = (char*)d_ws;
    f16* xh   = (f16*)W;
    f16* q_ws = (f16*)(W + 33554432);
    f16* Wall = (f16*)(W + 67108864);
    float* ball = (float*)(W + 75497472);
    float* kvg  = (float*)(W + 75513856);
    float* ksg  = (float*)(W + 76562432);

    prep<<<20480, 256, 0, stream>>>(x, xh, Wq, Wk, Wv, Wc, bq, bk, bv, bc,
                                    Wall, ball, kvg);

    gemm_qkv<<<dim3(128, 24), 256, 0, stream>>>(xh, Wall, ball, q_ws, kvg, ksg);

    y_kernel<<<dim3(BH, TSEQ / 128), 256, 0, stream>>>(q_ws, kvg, ksg, q_ws);

    gemm_out<<<dim3(128, 8), 256, 0, stream>>>(q_ws, Wall, ball, out);
}

// Round 11
// 213.482 us; speedup vs baseline: 1.3473x; 1.0594x over previous
//
#include <hip/hip_runtime.h>
#include <math.h>

#define EMBED 1024
#define HEADS 16
#define HD 64
#define BATCH 4
#define TSEQ 4096
#define BH (BATCH * HEADS)
#define MROWS (BATCH * TSEQ)   // 16384

typedef _Float16 f16;
typedef __attribute__((ext_vector_type(4))) _Float16 f16x4;
typedef __attribute__((ext_vector_type(8))) _Float16 f16x8;
typedef __attribute__((ext_vector_type(4))) float f32x4;

#define GLOBAL_AS __attribute__((address_space(1)))
#define LDS_AS __attribute__((address_space(3)))

__device__ __forceinline__ float elu1(float v) {
    return v > 0.f ? v + 1.f : __expf(v);
}

// XOR-swizzled element offset in a [rows][cols] f16 tile; 16B granules.
__device__ __forceinline__ int swzc(int row, int col, int cols) {
    int g = (col >> 3) ^ (row & 7);
    return row * cols + (g << 3) + (col & 7);
}

__device__ __forceinline__ f16x8 fragld(const f16* t, int row, int k, int cols) {
    return *(const f16x8*)&t[swzc(row, k, cols)];
}

__device__ __forceinline__ f32x4 mfma16(f16x8 a, f16x8 b, f32x4 c) {
    return __builtin_amdgcn_mfma_f32_16x16x32_f16(a, b, c, 0, 0, 0);
}

// async global->LDS, 16B per lane. lds dest must be wave-uniform base.
__device__ __forceinline__ void gld_lds16(const f16* g, f16* l) {
    __builtin_amdgcn_global_load_lds((const GLOBAL_AS void*)g, (LDS_AS void*)l, 16, 0, 0);
}

// ---------------------------------------------------------------------------
// prep: blocks [0,16384): x fp32 -> f16.  blocks [16384,20480): pack weights
// f16 + biases + zero kv/ks accumulators.
// ---------------------------------------------------------------------------
__global__ __launch_bounds__(256) void prep(
    const float* __restrict__ x, f16* __restrict__ xh,
    const float* __restrict__ Wq, const float* __restrict__ Wk,
    const float* __restrict__ Wv, const float* __restrict__ Wc,
    const float* __restrict__ bq, const float* __restrict__ bk,
    const float* __restrict__ bv, const float* __restrict__ bc,
    f16* __restrict__ Wall, float* __restrict__ ball, float* __restrict__ kvz)
{
    int bid = blockIdx.x;
    if (bid < 16384) {
        size_t i4 = (size_t)bid * 256 + threadIdx.x;
        float4 f = *(const float4*)&x[i4 * 4];
        f16x4 h = {(f16)f.x, (f16)f.y, (f16)f.z, (f16)f.w};
        *(f16x4*)&xh[i4 * 4] = h;
    } else {
        int i4 = (bid - 16384) * 256 + threadIdx.x;    // < 1048576
        int cls = i4 >> 18;
        const float* W = cls == 0 ? Wq : cls == 1 ? Wk : cls == 2 ? Wv : Wc;
        int off = (i4 & 0x3FFFF) * 4;
        float4 f = *(const float4*)&W[off];
        f16x4 h = {(f16)f.x, (f16)f.y, (f16)f.z, (f16)f.w};
        *(f16x4*)&Wall[(size_t)i4 * 4] = h;
        if (i4 < 4096) {
            int c2 = i4 >> 10;
            const float* bb = c2 == 0 ? bq : c2 == 1 ? bk : c2 == 2 ? bv : bc;
            ball[i4] = bb[i4 & 1023];
        }
        if (i4 < 66560) {   // (64*64*64 + 64*64)/4 floats of kv+ks
            *(float4*)&kvz[i4 * 4] = (float4){0.f, 0.f, 0.f, 0.f};
        }
    }
}

// ---------------------------------------------------------------------------
// gemm_kv: grid (128 m-tiles, 16 heads). C[128t x 128c] = xh @ [Wk_h;Wv_h]^T
// k=elu(C[:,0:64]+bk), v=C[:,64:128]+bv -> LDS transposed ->
// kvg[e][d] += v^T k (MFMA over 128 t), ksg[d] += sum_t k. (r10-proven path)
// ---------------------------------------------------------------------------
__global__ __launch_bounds__(256) void gemm_kv(
    const f16* __restrict__ xh, const f16* __restrict__ Wall,
    const float* __restrict__ ball,
    float* __restrict__ kvg, float* __restrict__ ksg)
{
    __shared__ __align__(16) f16 smem[2 * 128 * 64];   // As | Bs (32KB)
    f16* As = smem;
    f16* Bs = smem + 128 * 64;

    const int tid = threadIdx.x, lane = tid & 63, w = tid >> 6;
    const int wr = w >> 1, wc4 = w & 1, l15 = lane & 15, l4 = lane >> 4;

    const int m0 = blockIdx.x * 128;
    const int h = blockIdx.y;

    const int gcol = ((lane & 7) ^ (lane >> 3)) << 3;
    const int rsub = lane >> 3;
    const size_t arow = (size_t)(m0 + w * 32 + rsub) * EMBED + gcol;

    const int wrow = w * 32 + rsub;       // 0..127
    const int brow_idx = (wrow < 64) ? (1024 + h * 64 + wrow)
                                     : (2048 + h * 64 + (wrow - 64));
    const size_t brow = (size_t)brow_idx * EMBED + gcol;

    f32x4 acc[4][4];
    #pragma unroll
    for (int i = 0; i < 4; ++i)
        #pragma unroll
        for (int j = 0; j < 4; ++j) acc[i][j] = (f32x4){0.f, 0.f, 0.f, 0.f};

    for (int k0 = 0; k0 < EMBED; k0 += 64) {
        #pragma unroll
        for (int c = 0; c < 4; ++c) {
            gld_lds16(&xh[arow + (size_t)c * 8 * EMBED + k0], &As[(w * 4 + c) * 512]);
            gld_lds16(&Wall[brow + (size_t)c * 8 * EMBED + k0], &Bs[(w * 4 + c) * 512]);
        }
        __syncthreads();
        #pragma unroll
        for (int kk = 0; kk < 64; kk += 32) {
            f16x8 af[4], bf[4];
            #pragma unroll
            for (int i = 0; i < 4; ++i)
                af[i] = fragld(As, wr * 64 + i * 16 + l15, kk + l4 * 8, 64);
            #pragma unroll
            for (int j = 0; j < 4; ++j)
                bf[j] = fragld(Bs, wc4 * 64 + j * 16 + l15, kk + l4 * 8, 64);
            #pragma unroll
            for (int i = 0; i < 4; ++i)
                #pragma unroll
                for (int j = 0; j < 4; ++j)
                    acc[i][j] = mfma16(af[i], bf[j], acc[i][j]);
        }
        __syncthreads();
    }

    // kv epilogue: acc -> kt/vt LDS [64 d][128 t] (transposed, swizzled)
    f16* kt = As;
    f16* vt = Bs;
    const float* biasp = ball + (wc4 ? 2048 : 1024) + h * 64;
    #pragma unroll
    for (int j = 0; j < 4; ++j) {
        int d = j * 16 + l15;
        float bj = biasp[d];
        f16* dst = wc4 ? vt : kt;
        #pragma unroll
        for (int i = 0; i < 4; ++i) {
            int t0 = wr * 64 + i * 16 + l4 * 4;
            f16x4 hv;
            #pragma unroll
            for (int r = 0; r < 4; ++r) {
                float vv = acc[i][j][r] + bj;
                if (!wc4) vv = elu1(vv);
                hv[r] = (f16)vv;
            }
            *(f16x4*)&dst[swzc(d, t0, 128)] = hv;
        }
    }
    __syncthreads();

    // kvg[e][d] += sum_t v[t,e] k[t,d]; wave w owns e range [16w,16w+16)
    f32x4 kvacc[4];
    #pragma unroll
    for (int j = 0; j < 4; ++j) kvacc[j] = (f32x4){0.f, 0.f, 0.f, 0.f};
    #pragma unroll
    for (int tc = 0; tc < 4; ++tc) {
        f16x8 a = fragld(vt, 16 * w + l15, tc * 32 + l4 * 8, 128);
        #pragma unroll
        for (int j = 0; j < 4; ++j) {
            f16x8 bfr = fragld(kt, j * 16 + l15, tc * 32 + l4 * 8, 128);
            kvacc[j] = mfma16(a, bfr, kvacc[j]);
        }
    }
    float ksacc = 0.f;
    {
        int d = tid & 63, q4 = tid >> 6;
        #pragma unroll
        for (int t8 = 0; t8 < 32; t8 += 8) {
            f16x8 k8 = fragld(kt, d, q4 * 32 + t8, 128);
            #pragma unroll
            for (int e = 0; e < 8; ++e) ksacc += (float)k8[e];
        }
    }
    const int bh = (m0 >> 12) * HEADS + h;
    #pragma unroll
    for (int j = 0; j < 4; ++j)
        #pragma unroll
        for (int r = 0; r < 4; ++r)
            atomicAdd(&kvg[(size_t)bh * 4096 +
                           (size_t)(16 * w + l4 * 4 + r) * HD + j * 16 + l15],
                      kvacc[j][r]);
    atomicAdd(&ksg[bh * HD + (tid & 63)], ksacc);
}

// ---------------------------------------------------------------------------
// gemm_qy: grid (128 m-tiles, 8 q-classes). Block computes q for heads
// 2ny, 2ny+1 (cols [ny*128, +128)), then IN-BLOCK: z = 1/(q.ksum+1e-6),
// y = (q @ kv_h) * z, writes y (not q) coalesced. Eliminates the q HBM
// round trip and the separate y_kernel. Requires kvg/ksg complete (prior
// kernel). Per-wave y mapping: head hh = w>>1, e-half (w&1)*32, 8 t-tiles.
// ---------------------------------------------------------------------------
__global__ __launch_bounds__(256) void gemm_qy(
    const f16* __restrict__ xh, const f16* __restrict__ Wall,
    const float* __restrict__ ball,
    const float* __restrict__ kvg, const float* __restrict__ ksg,
    f16* __restrict__ y)
{
    __shared__ __align__(16) f16 smem[2 * 128 * 64];   // As|Bs -> qtile -> ytile
    __shared__ __align__(16) f16 kvs[2][64 * 64];      // per-head kv (f16, swz)
    __shared__ float kss[2][64];
    __shared__ float zs[128][2];
    f16* As = smem;
    f16* Bs = smem + 128 * 64;

    const int tid = threadIdx.x, lane = tid & 63, w = tid >> 6;
    const int wr = w >> 1, wc4 = w & 1, l15 = lane & 15, l4 = lane >> 4;

    const int m0 = blockIdx.x * 128;
    const int ny = blockIdx.y;            // 0..7
    const int n0 = ny * 128;
    const int bh0 = (m0 >> 12) * HEADS + 2 * ny;

    const int gcol = ((lane & 7) ^ (lane >> 3)) << 3;
    const int rsub = lane >> 3;
    const size_t arow = (size_t)(m0 + w * 32 + rsub) * EMBED + gcol;
    const size_t brow = (size_t)(n0 + w * 32 + rsub) * EMBED + gcol;

    f32x4 acc[4][4];
    #pragma unroll
    for (int i = 0; i < 4; ++i)
        #pragma unroll
        for (int j = 0; j < 4; ++j) acc[i][j] = (f32x4){0.f, 0.f, 0.f, 0.f};

    for (int k0 = 0; k0 < EMBED; k0 += 64) {
        #pragma unroll
        for (int c = 0; c < 4; ++c) {
            gld_lds16(&xh[arow + (size_t)c * 8 * EMBED + k0], &As[(w * 4 + c) * 512]);
            gld_lds16(&Wall[brow + (size_t)c * 8 * EMBED + k0], &Bs[(w * 4 + c) * 512]);
        }
        __syncthreads();
        #pragma unroll
        for (int kk = 0; kk < 64; kk += 32) {
            f16x8 af[4], bf[4];
            #pragma unroll
            for (int i = 0; i < 4; ++i)
                af[i] = fragld(As, wr * 64 + i * 16 + l15, kk + l4 * 8, 64);
            #pragma unroll
            for (int j = 0; j < 4; ++j)
                bf[j] = fragld(Bs, wc4 * 64 + j * 16 + l15, kk + l4 * 8, 64);
            #pragma unroll
            for (int i = 0; i < 4; ++i)
                #pragma unroll
                for (int j = 0; j < 4; ++j)
                    acc[i][j] = mfma16(af[i], bf[j], acc[i][j]);
        }
        __syncthreads();
    }

    // stage kv for both heads (fp32 -> f16, swizzled) + ksum
    #pragma unroll
    for (int c = 0; c < 8; ++c) {
        int idx = tid + c * 256;          // 0..2047
        int hh = idx >> 10;
        int rem = idx & 1023;
        int e = rem >> 4, d4 = (rem & 15) << 2;
        float4 f = *(const float4*)&kvg[(size_t)(bh0 + hh) * 4096 + e * 64 + d4];
        f16x4 hv = {(f16)f.x, (f16)f.y, (f16)f.z, (f16)f.w};
        *(f16x4*)&kvs[hh][swzc(e, d4, 64)] = hv;
    }
    if (tid < 128) kss[tid >> 6][tid & 63] = ksg[(bh0 + (tid >> 6)) * HD + (tid & 63)];

    // q epilogue -> qtile smem [128 t][128 c] swizzled
    #pragma unroll
    for (int j = 0; j < 4; ++j) {
        int c = wc4 * 64 + j * 16 + l15;
        float bj = ball[n0 + c];
        #pragma unroll
        for (int i = 0; i < 4; ++i) {
            #pragma unroll
            for (int r = 0; r < 4; ++r) {
                int t = wr * 64 + i * 16 + l4 * 4 + r;
                smem[swzc(t, c, 128)] = (f16)elu1(acc[i][j][r] + bj);
            }
        }
    }
    __syncthreads();

    // z[t][hh] = 1/(q[t, hh-head] . ksum + 1e-6); one thread per (t,hh)
    {
        int t = tid >> 1, hh = tid & 1;
        float s = 0.f;
        #pragma unroll
        for (int d8 = 0; d8 < 64; d8 += 8) {
            f16x8 qv = fragld(smem, t, hh * 64 + d8, 128);
            #pragma unroll
            for (int e = 0; e < 8; ++e) s += (float)qv[e] * kss[hh][d8 + e];
        }
        zs[t][hh] = 1.f / (s + 1e-6f);
    }

    // y^T[e][t] per head: wave w -> head hh=w>>1, e-half (w&1)*32
    const int hh = w >> 1;
    const int eh = (w & 1) * 32;
    f32x4 yacc[2][8];
    #pragma unroll
    for (int et = 0; et < 2; ++et)
        #pragma unroll
        for (int jn = 0; jn < 8; ++jn) yacc[et][jn] = (f32x4){0.f, 0.f, 0.f, 0.f};
    #pragma unroll
    for (int kk = 0; kk < 64; kk += 32) {
        f16x8 a0 = fragld(kvs[hh], eh + l15, kk + l4 * 8, 64);
        f16x8 a1 = fragld(kvs[hh], eh + 16 + l15, kk + l4 * 8, 64);
        #pragma unroll
        for (int jn = 0; jn < 8; ++jn) {
            f16x8 bq8 = fragld(smem, jn * 16 + l15, hh * 64 + kk + l4 * 8, 128);
            yacc[0][jn] = mfma16(a0, bq8, yacc[0][jn]);
            yacc[1][jn] = mfma16(a1, bq8, yacc[1][jn]);
        }
    }
    __syncthreads();   // qtile reads done; zs visible

    // scale by z, write ytile into smem [128 t][128 c] swizzled
    #pragma unroll
    for (int et = 0; et < 2; ++et) {
        #pragma unroll
        for (int jn = 0; jn < 8; ++jn) {
            int t = jn * 16 + l15;
            float z = zs[t][hh];
            int c0 = hh * 64 + eh + et * 16 + l4 * 4;
            f16x4 hv;
            #pragma unroll
            for (int r = 0; r < 4; ++r) hv[r] = (f16)(yacc[et][jn][r] * z);
            *(f16x4*)&smem[swzc(t, c0, 128)] = hv;
        }
    }
    __syncthreads();

    // coalesced y store
    #pragma unroll
    for (int p = 0; p < 8; ++p) {
        int idx = tid + p * 256;
        int row = idx >> 4, g8 = (idx & 15) << 3;
        f16x8 v = *(const f16x8*)&smem[swzc(row, g8, 128)];
        *(f16x8*)&y[(size_t)(m0 + row) * EMBED + n0 + g8] = v;
    }
}

// ---------------------------------------------------------------------------
// gemm_out: out[M,1024] = y @ Wc^T + bc (Wc = Wall rows 3072..4095), fp32 out.
// ---------------------------------------------------------------------------
__global__ __launch_bounds__(256) void gemm_out(
    const f16* __restrict__ y, const f16* __restrict__ Wall,
    const float* __restrict__ ball, float* __restrict__ out)
{
    __shared__ __align__(16) f16 As[128 * 64];
    __shared__ __align__(16) f16 Bs[128 * 64];

    const int tid = threadIdx.x, lane = tid & 63, w = tid >> 6;
    const int wr = w >> 1, wc4 = w & 1, l15 = lane & 15, l4 = lane >> 4;
    const int m0 = blockIdx.x * 128;
    const int n0 = blockIdx.y * 128;

    const int gcol = ((lane & 7) ^ (lane >> 3)) << 3;
    const int rsub = lane >> 3;
    const size_t arow = (size_t)(m0 + w * 32 + rsub) * EMBED + gcol;
    const size_t brow = (size_t)(3072 + n0 + w * 32 + rsub) * EMBED + gcol;

    f32x4 acc[4][4];
    #pragma unroll
    for (int i = 0; i < 4; ++i)
        #pragma unroll
        for (int j = 0; j < 4; ++j) acc[i][j] = (f32x4){0.f, 0.f, 0.f, 0.f};

    for (int k0 = 0; k0 < EMBED; k0 += 64) {
        #pragma unroll
        for (int c = 0; c < 4; ++c) {
            gld_lds16(&y[arow + (size_t)c * 8 * EMBED + k0], &As[(w * 4 + c) * 512]);
            gld_lds16(&Wall[brow + (size_t)c * 8 * EMBED + k0], &Bs[(w * 4 + c) * 512]);
        }
        __syncthreads();
        #pragma unroll
        for (int kk = 0; kk < 64; kk += 32) {
            f16x8 af[4], bf[4];
            #pragma unroll
            for (int i = 0; i < 4; ++i)
                af[i] = fragld(As, wr * 64 + i * 16 + l15, kk + l4 * 8, 64);
            #pragma unroll
            for (int j = 0; j < 4; ++j)
                bf[j] = fragld(Bs, wc4 * 64 + j * 16 + l15, kk + l4 * 8, 64);
            #pragma unroll
            for (int i = 0; i < 4; ++i)
                #pragma unroll
                for (int j = 0; j < 4; ++j)
                    acc[i][j] = mfma16(af[i], bf[j], acc[i][j]);
        }
        __syncthreads();
    }

    #pragma unroll
    for (int j = 0; j < 4; ++j) {
        int n = n0 + wc4 * 64 + j * 16 + l15;
        float bj = ball[3072 + n];
        #pragma unroll
        for (int i = 0; i < 4; ++i) {
            #pragma unroll
            for (int r = 0; r < 4; ++r) {
                int m = m0 + wr * 64 + i * 16 + l4 * 4 + r;
                out[(size_t)m * EMBED + n] = acc[i][j][r] + bj;
            }
        }
    }
}

// ---------------------------------------------------------------------------
extern "C" void kernel_launch(void* const* d_in, const int* in_sizes, int n_in,
                              void* d_out, int out_size, void* d_ws, size_t ws_size,
                              hipStream_t stream) {
    (void)in_sizes; (void)n_in; (void)out_size; (void)ws_size;
    const float* x  = (const float*)d_in[0];
    const float* Wq = (const float*)d_in[1];
    const float* bq = (const float*)d_in[2];
    const float* Wk = (const float*)d_in[3];
    const float* bk = (const float*)d_in[4];
    const float* Wv = (const float*)d_in[5];
    const float* bv = (const float*)d_in[6];
    const float* Wc = (const float*)d_in[7];
    const float* bc = (const float*)d_in[8];
    float* out = (float*)d_out;

    // workspace (~77 MB): xh 32MB | y 32MB | Wall 8MB | ball | kvg | ksg
    char* W = (char*)d_ws;
    f16* xh   = (f16*)W;
    f16* y_ws = (f16*)(W + 33554432);
    f16* Wall = (f16*)(W + 67108864);
    float* ball = (float*)(W + 75497472);
    float* kvg  = (float*)(W + 75513856);
    float* ksg  = (float*)(W + 76562432);

    prep<<<20480, 256, 0, stream>>>(x, xh, Wq, Wk, Wv, Wc, bq, bk, bv, bc,
                                    Wall, ball, kvg);

    gemm_kv<<<dim3(128, 16), 256, 0, stream>>>(xh, Wall, ball, kvg, ksg);

    gemm_qy<<<dim3(128, 8), 256, 0, stream>>>(xh, Wall, ball, kvg, ksg, y_ws);

    gemm_out<<<dim3(128, 8), 256, 0, stream>>>(y_ws, Wall, ball, out);
}